// Round 1
// 4659.773 us; speedup vs baseline: 1.2057x; 1.2057x over previous
//
#include <hip/hip_runtime.h>

typedef __bf16 bf16_t;
typedef __bf16 bf16x8 __attribute__((ext_vector_type(8)));
typedef float f32x4 __attribute__((ext_vector_type(4)));
typedef unsigned long long u64;

#define B_ 64
#define T_ 256
#define F_ 1024
#define H_ 1024
#define G4_ 4096
#define NBLK_ 192
#define LPAD_ 1032   // row stride (elems): 2064B = 16B-aligned, worst 2-way LDS conflict (free)

#define MFMA16 __builtin_amdgcn_mfma_f32_16x16x32_bf16

__device__ __forceinline__ float sig_fast(float x) { return 1.f / (1.f + __expf(-x)); }
__device__ __forceinline__ float tanh_fast(float x) {
    float e = __expf(2.f * x);
    return 1.f - 2.f / (e + 1.f);
}
__device__ __forceinline__ float waveReduceSum(float v) {
    #pragma unroll
    for (int off = 32; off > 0; off >>= 1) v += __shfl_xor(v, off);
    return v;
}

// ---- agent-coherent (sc0 sc1) helpers: per-instruction coherence, NO cache fences ----
__device__ __forceinline__ void atom_store_u32(unsigned* p, unsigned v) {
    __hip_atomic_store(p, v, __ATOMIC_RELAXED, __HIP_MEMORY_SCOPE_AGENT);
}
// 16B h-fragment read that bypasses (possibly stale) L1/L2 and reads the LLC.
__device__ __forceinline__ bf16x8 load_coh_frag(const bf16_t* p) {
    u64 lo = __hip_atomic_load((u64*)p,     __ATOMIC_RELAXED, __HIP_MEMORY_SCOPE_AGENT);
    u64 hi = __hip_atomic_load((u64*)p + 1, __ATOMIC_RELAXED, __HIP_MEMORY_SCOPE_AGENT);
    union { u64 q[2]; bf16x8 v; } u;
    u.q[0] = lo; u.q[1] = hi;
    return u.v;
}
__device__ __forceinline__ unsigned bf16_bits(float f) {
    unsigned short s = __builtin_bit_cast(unsigned short, (bf16_t)f);
    return (unsigned)s;
}

// ---- all-to-all flag barrier, FENCE-FREE ----
// h data is exchanged with agent-scope (sc0 sc1) write-through stores and
// LLC-direct loads, so no buffer_wbl2/buffer_inv is needed. Ordering argument:
// __syncthreads drains vmcnt(0) for every wave before s_barrier, so all h
// atomic stores have reached the LLC (their point of coherency) before
// thread0 publishes the stamp (also a write-through agent store). Consumers
// see the stamp, then read h straight from LLC.
__device__ __forceinline__ void group_barrier(unsigned* arr, int idx, int n,
                                              unsigned stamp, unsigned* flag) {
    __syncthreads();
    if (threadIdx.x == 0)
        __hip_atomic_store(&arr[idx], stamp, __ATOMIC_RELAXED, __HIP_MEMORY_SCOPE_AGENT);
    if (threadIdx.x < (unsigned)n) {
        int spins = 0;
        while (__hip_atomic_load(&arr[threadIdx.x], __ATOMIC_RELAXED,
                                 __HIP_MEMORY_SCOPE_AGENT) < stamp) {
            __builtin_amdgcn_s_sleep(1);
            if ((++spins & 1023) == 0) {
                if (__hip_atomic_load(flag, __ATOMIC_RELAXED, __HIP_MEMORY_SCOPE_AGENT)) break;
                if (spins > 2000000) {  // ~0.5 s: latch diagnostic, never hang
                    __hip_atomic_fetch_or(flag, 1u, __ATOMIC_RELAXED, __HIP_MEMORY_SCOPE_AGENT);
                    break;
                }
            }
        }
    }
    __syncthreads();
}

// ---------------- small prep kernels ----------------

__global__ void cast_kernel(const float* __restrict__ src, bf16_t* __restrict__ dst, int n) {
    int i = blockIdx.x * 256 + threadIdx.x;
    if (i < n) dst[i] = (bf16_t)src[i];
}

__global__ void bias_sum_kernel(const float* __restrict__ a, const float* __restrict__ b,
                                float* __restrict__ dst, int n) {
    int i = blockIdx.x * 256 + threadIdx.x;
    if (i < n) dst[i] = a[i] + b[i];
}

// w1 [1024,64] -> w1T bf16 [64,1024]
__global__ void w1t_kernel(const float* __restrict__ w1, bf16_t* __restrict__ w1T) {
    int i = blockIdx.x * 256 + threadIdx.x;  // 65536
    int j = i >> 10, u = i & 1023;
    w1T[i] = (bf16_t)w1[u * 64 + j];
}

// cov_temp[b,t] = (b%32==31)?0 : max(0, (sum_f x^2 - (sum_f x)^2/F)/T)
__global__ __launch_bounds__(256) void cov1_kernel(const float* __restrict__ x, float* __restrict__ ct) {
    int row = blockIdx.x * 4 + (threadIdx.x >> 6);  // b*T+t
    int lane = threadIdx.x & 63;
    const float* xr = x + (size_t)row * F_;
    float s1 = 0.f, s2 = 0.f;
    for (int f = lane; f < F_; f += 64) { float v = xr[f]; s1 += v; s2 += v * v; }
    s1 = waveReduceSum(s1);
    s2 = waveReduceSum(s2);
    if (lane == 0) {
        int b = row >> 8;
        float c = (s2 - s1 * s1 * (1.f / F_)) * (1.f / T_);
        ct[row] = ((b & 31) == 31) ? 0.f : fmaxf(c, 0.f);
    }
}

// cov_chan[b,f] (bf16) = (b%32==31)?0 : max(0, (sum_t x^2 - (sum_t x)^2/T)/F)
__global__ __launch_bounds__(256) void cov2_kernel(const float* __restrict__ x,
                                                   bf16_t* __restrict__ ccb) {
    int b = blockIdx.x;
    #pragma unroll
    for (int j = 0; j < 4; ++j) {
        int f = threadIdx.x + j * 256;
        float s1 = 0.f, s2 = 0.f;
        for (int t = 0; t < T_; ++t) {
            float v = x[((size_t)b * T_ + t) * F_ + f];
            s1 += v; s2 += v * v;
        }
        float c = (s2 - s1 * s1 * (1.f / T_)) * (1.f / F_);
        if ((b & 31) == 31) c = 0.f;
        ccb[b * F_ + f] = (bf16_t)fmaxf(c, 0.f);
    }
}

// ---------------- generic MFMA GEMM: C[M,N] = A[M,K] * B[N,K]^T (+bias) ----------------
__global__ __launch_bounds__(256) void gemm_bt_kernel(
    const bf16_t* __restrict__ A, const bf16_t* __restrict__ B,
    const float* __restrict__ bias, float* __restrict__ C,
    int M, int N, int K)
{
    const int wave = threadIdx.x >> 6;
    const int lane = threadIdx.x & 63;
    const int ln15 = lane & 15;
    const int quad = lane >> 4;
    const int n_base = blockIdx.x * 64;
    const int m_wave = blockIdx.y * 128 + wave * 32;

    f32x4 acc[2][4] = {};

    int rowA0 = m_wave + ln15;       if (rowA0 >= M) rowA0 = M - 1;
    int rowA1 = m_wave + 16 + ln15;  if (rowA1 >= M) rowA1 = M - 1;
    const bf16_t* Arow0 = A + (size_t)rowA0 * K + quad * 8;
    const bf16_t* Arow1 = A + (size_t)rowA1 * K + quad * 8;
    const bf16_t* Brow0 = B + (size_t)(n_base + 0 * 16 + ln15) * K + quad * 8;
    const bf16_t* Brow1 = B + (size_t)(n_base + 1 * 16 + ln15) * K + quad * 8;
    const bf16_t* Brow2 = B + (size_t)(n_base + 2 * 16 + ln15) * K + quad * 8;
    const bf16_t* Brow3 = B + (size_t)(n_base + 3 * 16 + ln15) * K + quad * 8;

    for (int k0 = 0; k0 < K; k0 += 32) {
        bf16x8 a0 = *(const bf16x8*)(Arow0 + k0);
        bf16x8 a1 = *(const bf16x8*)(Arow1 + k0);
        bf16x8 b0 = *(const bf16x8*)(Brow0 + k0);
        bf16x8 b1 = *(const bf16x8*)(Brow1 + k0);
        bf16x8 b2 = *(const bf16x8*)(Brow2 + k0);
        bf16x8 b3 = *(const bf16x8*)(Brow3 + k0);
        acc[0][0] = MFMA16(a0, b0, acc[0][0], 0, 0, 0);
        acc[0][1] = MFMA16(a0, b1, acc[0][1], 0, 0, 0);
        acc[0][2] = MFMA16(a0, b2, acc[0][2], 0, 0, 0);
        acc[0][3] = MFMA16(a0, b3, acc[0][3], 0, 0, 0);
        acc[1][0] = MFMA16(a1, b0, acc[1][0], 0, 0, 0);
        acc[1][1] = MFMA16(a1, b1, acc[1][1], 0, 0, 0);
        acc[1][2] = MFMA16(a1, b2, acc[1][2], 0, 0, 0);
        acc[1][3] = MFMA16(a1, b3, acc[1][3], 0, 0, 0);
    }

    #pragma unroll
    for (int s = 0; s < 2; ++s) {
        #pragma unroll
        for (int g = 0; g < 4; ++g) {
            int col = n_base + g * 16 + ln15;
            float bv = bias ? bias[col] : 0.f;
            #pragma unroll
            for (int r = 0; r < 4; ++r) {
                int row = m_wave + s * 16 + quad * 4 + r;
                if (row < M) C[(size_t)row * N + col] = acc[s][g][r] + bv;
            }
        }
    }
}

// ---------------- persistent dual-LSTM recurrence ----------------
// blocks 0..127:  LSTM1, 8 units each; LDS = Wih slice (rows 0..31) + Whh slice (rows 32..63)
//                 row n -> (gate n>>3, unit n&7); fused x-gemm + h-gemm. Barrier group A (128 flags).
// blocks 128..191: LSTM2, 16 units each; LDS = Whh2 slice (64 rows, row n -> gate n>>4, unit n&15);
//                 xg2 = ct[b,t]*v[b,col] + bias2 (rank-1). Barrier group B (64 flags).
// Cross-block h exchange is fence-free: h stores are packed-u32 agent atomics
// (write-through to LLC), h loads are u64 agent atomics (LLC-direct). No
// __threadfence anywhere in the recurrence -> no per-step buffer_wbl2/buffer_inv.
__global__ __launch_bounds__(256, 1) void lstm_recur_kernel(
    const bf16_t* __restrict__ xb,    // [B,T,F] bf16
    const float*  __restrict__ ct,    // [B,T]
    const float*  __restrict__ v,     // [B,4096] fp32
    const float*  __restrict__ b1s,   // [4096]
    const float*  __restrict__ b2s,   // [4096]
    const float*  __restrict__ wih1,  // [4096,1024] fp32
    const float*  __restrict__ whh1,  // [4096,1024] fp32
    const float*  __restrict__ whh2,  // [4096,1024] fp32
    bf16_t* __restrict__ h1buf,       // [2][B][H] bf16
    bf16_t* __restrict__ h2buf,
    bf16_t* __restrict__ enc,         // [B,T,H] bf16
    float*  __restrict__ outl,        // [B,H] fp32
    unsigned* __restrict__ bar)
{
    __shared__ bf16_t wlds[64 * LPAD_];  // 132096 B

    const int blk  = blockIdx.x;
    const int is2  = (blk >= 128);
    const int wave = threadIdx.x >> 6;
    const int lane = threadIdx.x & 63;
    const int ln15 = lane & 15;
    const int quad = lane >> 4;
    const int bw   = wave * 16;

    unsigned* arr  = is2 ? (bar + 128) : bar;   // packed per-block stamp words
    const int gidx = is2 ? (blk - 128) : blk;
    const int gn   = is2 ? 64 : 128;
    unsigned* flag = bar + 224;                 // timeout diagnostic

    int u0;
    if (!is2) {
        u0 = blk * 8;
        for (int i = threadIdx.x; i < 2 * 32 * 128; i += 256) {
            int mat = i >> 12;
            int rem = i & 4095;
            int n = rem >> 7;
            int kc = (rem & 127) * 8;
            int gate = n >> 3, unit = n & 7;
            const float* src = (mat ? whh1 : wih1) + (size_t)(gate * 1024 + u0 + unit) * H_ + kc;
            float4 f0 = *(const float4*)(src);
            float4 f1 = *(const float4*)(src + 4);
            bf16x8 w;
            w[0] = (bf16_t)f0.x; w[1] = (bf16_t)f0.y; w[2] = (bf16_t)f0.z; w[3] = (bf16_t)f0.w;
            w[4] = (bf16_t)f1.x; w[5] = (bf16_t)f1.y; w[6] = (bf16_t)f1.z; w[7] = (bf16_t)f1.w;
            *(bf16x8*)&wlds[(mat * 32 + n) * LPAD_ + kc] = w;
        }
        // zero-init h1 buf0 (write-through so it's visible without fences)
        for (int i = threadIdx.x; i < 64 * 4; i += 256)
            atom_store_u32((unsigned*)h1buf + (size_t)(i >> 2) * (H_ / 2) + (u0 >> 1) + (i & 3), 0u);
    } else {
        u0 = (blk - 128) * 16;
        for (int i = threadIdx.x; i < 64 * 128; i += 256) {
            int n = i >> 7;
            int kc = (i & 127) * 8;
            int gate = n >> 4, unit = n & 15;
            const float* src = whh2 + (size_t)(gate * 1024 + u0 + unit) * H_ + kc;
            float4 f0 = *(const float4*)(src);
            float4 f1 = *(const float4*)(src + 4);
            bf16x8 w;
            w[0] = (bf16_t)f0.x; w[1] = (bf16_t)f0.y; w[2] = (bf16_t)f0.z; w[3] = (bf16_t)f0.w;
            w[4] = (bf16_t)f1.x; w[5] = (bf16_t)f1.y; w[6] = (bf16_t)f1.z; w[7] = (bf16_t)f1.w;
            *(bf16x8*)&wlds[n * LPAD_ + kc] = w;
        }
        for (int i = threadIdx.x; i < 64 * 8; i += 256)
            atom_store_u32((unsigned*)h2buf + (size_t)(i >> 3) * (H_ / 2) + (u0 >> 1) + (i & 7), 0u);
    }

    // per-thread constants
    float bias0 = 0.f, bias1 = 0.f;
    float vreg[4][4];
    float b2reg[4];
    if (!is2) {
        int col0 = (ln15 < 8) ? (u0 + ln15) : (1024 + u0 + ln15 - 8);
        int col1 = (ln15 < 8) ? (2048 + u0 + ln15) : (3072 + u0 + ln15 - 8);
        bias0 = b1s[col0];
        bias1 = b1s[col1];
    } else {
        #pragma unroll
        for (int g = 0; g < 4; ++g) {
            int colg = g * 1024 + u0 + ln15;
            b2reg[g] = b2s[colg];
            #pragma unroll
            for (int r = 0; r < 4; ++r)
                vreg[g][r] = v[(size_t)(bw + quad * 4 + r) * G4_ + colg];
        }
    }

    unsigned stamp = 1;
    group_barrier(arr, gidx, gn, stamp, flag); stamp++;  // zeros + staging visible

    const bf16_t* hread  = is2 ? h2buf : h1buf;
    bf16_t*       hwrite = (is2 ? h2buf : h1buf) + B_ * H_;

    float c_st[4] = {0.f, 0.f, 0.f, 0.f};

    if (!is2) {
        for (int t = 0; t < T_; ++t) {
            f32x4 acc0 = {}, acc1 = {};
            const bf16_t* xA = xb + ((size_t)(bw + ln15) * T_ + t) * F_ + quad * 8;
            const bf16_t* hA = hread + (size_t)(bw + ln15) * H_ + quad * 8;
            const bf16_t* xB0 = &wlds[(0 + ln15) * LPAD_ + quad * 8];
            const bf16_t* xB1 = &wlds[(16 + ln15) * LPAD_ + quad * 8];
            const bf16_t* hB0 = &wlds[(32 + ln15) * LPAD_ + quad * 8];
            const bf16_t* hB1 = &wlds[(48 + ln15) * LPAD_ + quad * 8];
            #pragma unroll 8
            for (int k0 = 0; k0 < H_; k0 += 32) {
                bf16x8 ax = *(const bf16x8*)(xA + k0);
                bf16x8 ah = load_coh_frag(hA + k0);
                acc0 = MFMA16(ax, *(const bf16x8*)(xB0 + k0), acc0, 0, 0, 0);
                acc1 = MFMA16(ax, *(const bf16x8*)(xB1 + k0), acc1, 0, 0, 0);
                acc0 = MFMA16(ah, *(const bf16x8*)(hB0 + k0), acc0, 0, 0, 0);
                acc1 = MFMA16(ah, *(const bf16x8*)(hB1 + k0), acc1, 0, 0, 0);
            }
            #pragma unroll
            for (int r = 0; r < 4; ++r) {
                int b = bw + quad * 4 + r;
                float p0 = acc0[r] + bias0;          // i (ln15<8) or f (ln15>=8)
                float p1 = acc1[r] + bias1;          // g or o
                float q0 = __shfl_xor(p0, 8);
                float q1 = __shfl_xor(p1, 8);
                float ig = (ln15 < 8) ? p0 : q0;
                float fg = (ln15 < 8) ? q0 : p0;
                float gg = (ln15 < 8) ? p1 : q1;
                float og = (ln15 < 8) ? q1 : p1;
                ig = sig_fast(ig); fg = sig_fast(fg);
                gg = tanh_fast(gg); og = sig_fast(og);
                float c = fg * c_st[r] + ig * gg;
                c_st[r] = c;
                float h = og * tanh_fast(c);
                unsigned hv = bf16_bits(h);
                unsigned pv = __shfl_xor(hv, 1);     // partner unit's h (ln15 xor 1)
                if ((ln15 & 1) == 0 && ln15 < 8)
                    atom_store_u32((unsigned*)hwrite + (size_t)b * (H_ / 2) + ((u0 + ln15) >> 1),
                                   hv | (pv << 16));
                if (ln15 < 8 && t == T_ - 1) outl[(size_t)b * H_ + u0 + ln15] = h;
            }
            group_barrier(arr, gidx, gn, stamp, flag); stamp++;
            bf16_t* tmp = (bf16_t*)hread; hread = hwrite; hwrite = tmp;
        }
    } else {
        for (int t = 0; t < T_; ++t) {
            f32x4 acc[4] = {};
            const bf16_t* hA = hread + (size_t)(bw + ln15) * H_ + quad * 8;
            const bf16_t* B0 = &wlds[(0 * 16 + ln15) * LPAD_ + quad * 8];
            const bf16_t* B1 = &wlds[(1 * 16 + ln15) * LPAD_ + quad * 8];
            const bf16_t* B2 = &wlds[(2 * 16 + ln15) * LPAD_ + quad * 8];
            const bf16_t* B3 = &wlds[(3 * 16 + ln15) * LPAD_ + quad * 8];
            #pragma unroll 8
            for (int k0 = 0; k0 < H_; k0 += 32) {
                bf16x8 a = load_coh_frag(hA + k0);
                acc[0] = MFMA16(a, *(const bf16x8*)(B0 + k0), acc[0], 0, 0, 0);
                acc[1] = MFMA16(a, *(const bf16x8*)(B1 + k0), acc[1], 0, 0, 0);
                acc[2] = MFMA16(a, *(const bf16x8*)(B2 + k0), acc[2], 0, 0, 0);
                acc[3] = MFMA16(a, *(const bf16x8*)(B3 + k0), acc[3], 0, 0, 0);
            }
            #pragma unroll
            for (int r = 0; r < 4; ++r) {
                int b = bw + quad * 4 + r;
                float cts = ct[b * T_ + t];
                float ig = sig_fast(acc[0][r] + cts * vreg[0][r] + b2reg[0]);
                float fg = sig_fast(acc[1][r] + cts * vreg[1][r] + b2reg[1]);
                float gg = tanh_fast(acc[2][r] + cts * vreg[2][r] + b2reg[2]);
                float og = sig_fast(acc[3][r] + cts * vreg[3][r] + b2reg[3]);
                float c = fg * c_st[r] + ig * gg;
                c_st[r] = c;
                float h = og * tanh_fast(c);
                unsigned hv = bf16_bits(h);
                unsigned pv = __shfl_xor(hv, 1);
                if ((ln15 & 1) == 0) {
                    unsigned word = hv | (pv << 16);
                    atom_store_u32((unsigned*)hwrite + (size_t)b * (H_ / 2) + ((u0 + ln15) >> 1), word);
                    // enc is consumed only after kernel end -> normal (dirty-L2) store is fine
                    *((unsigned*)enc + ((size_t)b * T_ + t) * (H_ / 2) + ((u0 + ln15) >> 1)) = word;
                }
            }
            group_barrier(arr, gidx, gn, stamp, flag); stamp++;
            bf16_t* tmp = (bf16_t*)hread; hread = hwrite; hwrite = tmp;
        }
    }
}

// ---------------- attention epilogue ----------------

__global__ __launch_bounds__(256) void p1_kernel(const bf16_t* __restrict__ enc,
                                                 float* __restrict__ Msm, float* __restrict__ Ssm) {
    int b = blockIdx.x;
    #pragma unroll
    for (int j = 0; j < 4; ++j) {
        int u = threadIdx.x + j * 256;
        const bf16_t* e = enc + (size_t)b * T_ * H_ + u;
        float m = -1e30f;
        for (int t = 0; t < T_; ++t) m = fmaxf(m, (float)e[(size_t)t * H_]);
        float s = 0.f;
        for (int t = 0; t < T_; ++t) s += __expf((float)e[(size_t)t * H_] - m);
        Msm[b * H_ + u] = m;
        Ssm[b * H_ + u] = s;
    }
}

__global__ __launch_bounds__(256) void p2_kernel(
    const bf16_t* __restrict__ enc, const float* __restrict__ Msm, const float* __restrict__ Ssm,
    const float* __restrict__ outl, const float* __restrict__ w_attn,
    bf16_t* __restrict__ saa, float* __restrict__ tapre) {
    int row = blockIdx.x;   // b*T+t
    int b = row >> 8;
    const bf16_t* erow = enc + (size_t)row * H_;
    float tsum = 0.f;
    for (int u = threadIdx.x; u < H_; u += 256) {
        float e = (float)erow[u];
        float sp = __expf(e - Msm[b * H_ + u]) / Ssm[b * H_ + u];
        saa[(size_t)row * H_ + u] = (bf16_t)(outl[b * H_ + u] * (sp + 1.f));
        tsum += tanh_fast(e) * w_attn[u];
    }
    tsum = waveReduceSum(tsum);
    __shared__ float red[4];
    if ((threadIdx.x & 63) == 0) red[threadIdx.x >> 6] = tsum;
    __syncthreads();
    if (threadIdx.x == 0) tapre[row] = red[0] + red[1] + red[2] + red[3];
}

// final: det = sigmoid(relu(r1)@w2 + b2); out = det*(1+sigmoid(tapre+b_attn))  [fp32 out]
__global__ __launch_bounds__(256) void p4_kernel(
    const float* __restrict__ r1, const float* __restrict__ w2, const float* __restrict__ b2,
    const float* __restrict__ tapre, const float* __restrict__ b_attn,
    const unsigned* __restrict__ flag, float* __restrict__ out) {
    int row = blockIdx.x * 4 + (threadIdx.x >> 6);
    int lane = threadIdx.x & 63;
    float vsum = fmaxf(r1[(size_t)row * 64 + lane], 0.f) * w2[lane];
    vsum = waveReduceSum(vsum);
    if (lane == 0) {
        float det = sig_fast(vsum + b2[0]);
        float ta = sig_fast(tapre[row] + b_attn[0]);
        out[row] = det * (1.f + ta) + 1000.f * (float)(*flag);
    }
}

// ---------------- launcher ----------------

extern "C" void kernel_launch(void* const* d_in, const int* in_sizes, int n_in,
                              void* d_out, int out_size, void* d_ws, size_t ws_size,
                              hipStream_t stream) {
    const float* x      = (const float*)d_in[0];
    const float* W_ih1  = (const float*)d_in[1];
    const float* W_hh1  = (const float*)d_in[2];
    const float* b_ih1  = (const float*)d_in[3];
    const float* b_hh1  = (const float*)d_in[4];
    const float* W_ih2  = (const float*)d_in[5];
    const float* W_hh2  = (const float*)d_in[6];
    const float* b_ih2  = (const float*)d_in[7];
    const float* b_hh2  = (const float*)d_in[8];
    const float* w_attn = (const float*)d_in[9];
    const float* b_attn = (const float*)d_in[10];
    const float* w1     = (const float*)d_in[11];
    const float* b1     = (const float*)d_in[12];
    const float* w2     = (const float*)d_in[13];
    const float* b2     = (const float*)d_in[14];

    char* ws = (char*)d_ws;
    size_t off = 0;
    auto alloc = [&](size_t bytes) { size_t r = off; off = (off + bytes + 255) & ~(size_t)255; return r; };

    size_t o_bar  = alloc(1024);                      // 128+64 flags + diag flag
    size_t o_wih2 = alloc((size_t)G4_ * H_ * 2);      // 8 MB bf16 (for v-gemm)
    size_t o_xb   = alloc((size_t)B_ * T_ * F_ * 2);  // 32 MB
    size_t o_b1s  = alloc(G4_ * 4);
    size_t o_b2s  = alloc(G4_ * 4);
    size_t o_ct   = alloc(B_ * T_ * 4);
    size_t o_ccb  = alloc(B_ * F_ * 2);
    size_t o_v    = alloc((size_t)B_ * G4_ * 4);      // 1 MB
    size_t o_h1   = alloc(2 * B_ * H_ * 2);
    size_t o_h2   = alloc(2 * B_ * H_ * 2);
    size_t o_outl = alloc(B_ * H_ * 4);
    size_t o_w1t  = alloc(64 * H_ * 2);
    size_t o_msm  = alloc(B_ * H_ * 4);
    size_t o_ssm  = alloc(B_ * H_ * 4);
    size_t o_tap  = alloc(B_ * T_ * 4);
    size_t o_enc  = alloc((size_t)B_ * T_ * H_ * 2);  // 32 MB bf16
    size_t o_saa  = o_xb;                             // alias: xb dead after recurrence
    size_t o_r1   = o_enc;                            // alias: enc dead after p2

    if (ws_size < off) return;  // fail loudly as absmax mismatch, never a fault

    unsigned* bar  = (unsigned*)(ws + o_bar);
    bf16_t* wih2b  = (bf16_t*)(ws + o_wih2);
    bf16_t* xb     = (bf16_t*)(ws + o_xb);
    float*  b1s    = (float*)(ws + o_b1s);
    float*  b2s    = (float*)(ws + o_b2s);
    float*  ctp    = (float*)(ws + o_ct);
    bf16_t* ccb    = (bf16_t*)(ws + o_ccb);
    float*  vbuf   = (float*)(ws + o_v);
    bf16_t* h1     = (bf16_t*)(ws + o_h1);
    bf16_t* h2     = (bf16_t*)(ws + o_h2);
    float*  outl   = (float*)(ws + o_outl);
    bf16_t* w1t    = (bf16_t*)(ws + o_w1t);
    float*  msm    = (float*)(ws + o_msm);
    float*  ssm    = (float*)(ws + o_ssm);
    float*  tap    = (float*)(ws + o_tap);
    bf16_t* encp   = (bf16_t*)(ws + o_enc);
    bf16_t* saa    = (bf16_t*)(ws + o_saa);
    float*  r1     = (float*)(ws + o_r1);

    hipMemsetAsync(ws + o_bar, 0, 1024, stream);

    int n = G4_ * H_;
    cast_kernel<<<(n + 255) / 256, 256, 0, stream>>>(W_ih2, wih2b, n);
    n = B_ * T_ * F_;
    cast_kernel<<<(n + 255) / 256, 256, 0, stream>>>(x, xb, n);
    bias_sum_kernel<<<16, 256, 0, stream>>>(b_ih1, b_hh1, b1s, G4_);
    bias_sum_kernel<<<16, 256, 0, stream>>>(b_ih2, b_hh2, b2s, G4_);
    cov1_kernel<<<B_ * T_ / 4, 256, 0, stream>>>(x, ctp);
    cov2_kernel<<<B_, 256, 0, stream>>>(x, ccb);
    w1t_kernel<<<256, 256, 0, stream>>>(w1, w1t);

    // v = cov_chan * Wih2^T (fp32 out)
    gemm_bt_kernel<<<dim3(G4_ / 64, 1), 256, 0, stream>>>(ccb, wih2b, nullptr, vbuf, B_, G4_, H_);

    lstm_recur_kernel<<<NBLK_, 256, 0, stream>>>(
        xb, ctp, vbuf, b1s, b2s, W_ih1, W_hh1, W_hh2, h1, h2, encp, outl, bar);

    p1_kernel<<<B_, 256, 0, stream>>>(encp, msm, ssm);
    p2_kernel<<<B_ * T_, 256, 0, stream>>>(encp, msm, ssm, outl, w_attn, saa, tap);
    // r1 = saa * w1T^T + b1 (fp32 out)
    gemm_bt_kernel<<<dim3(1, B_ * T_ / 128), 256, 0, stream>>>(saa, w1t, b1, r1, B_ * T_, 64, H_);
    p4_kernel<<<B_ * T_ / 4, 256, 0, stream>>>(r1, w2, b2, tap, b_attn, bar + 224, (float*)d_out);

    (void)in_sizes; (void)n_in; (void)out_size;
}

// Round 2
// 4521.236 us; speedup vs baseline: 1.2427x; 1.0306x over previous
//
#include <hip/hip_runtime.h>

typedef __bf16 bf16_t;
typedef __bf16 bf16x8 __attribute__((ext_vector_type(8)));
typedef float f32x4 __attribute__((ext_vector_type(4)));
typedef unsigned long long u64;

#define B_ 64
#define T_ 256
#define F_ 1024
#define H_ 1024
#define G4_ 4096
#define NBLK_ 192
#define LPAD_ 1032   // row stride (elems): 2064B = 16B-aligned, worst 2-way LDS conflict (free)

#define MFMA16 __builtin_amdgcn_mfma_f32_16x16x32_bf16

__device__ __forceinline__ float sig_fast(float x) { return 1.f / (1.f + __expf(-x)); }
__device__ __forceinline__ float tanh_fast(float x) {
    float e = __expf(2.f * x);
    return 1.f - 2.f / (e + 1.f);
}
__device__ __forceinline__ float waveReduceSum(float v) {
    #pragma unroll
    for (int off = 32; off > 0; off >>= 1) v += __shfl_xor(v, off);
    return v;
}

// ---- agent-coherent (sc0 sc1) helpers: per-instruction coherence, NO cache fences ----
__device__ __forceinline__ void atom_store_u32(unsigned* p, unsigned v) {
    __hip_atomic_store(p, v, __ATOMIC_RELAXED, __HIP_MEMORY_SCOPE_AGENT);
}
// 16B h-fragment read that bypasses (possibly stale) L1/L2 and reads the LLC.
__device__ __forceinline__ bf16x8 load_coh_frag(const bf16_t* p) {
    u64 lo = __hip_atomic_load((u64*)p,     __ATOMIC_RELAXED, __HIP_MEMORY_SCOPE_AGENT);
    u64 hi = __hip_atomic_load((u64*)p + 1, __ATOMIC_RELAXED, __HIP_MEMORY_SCOPE_AGENT);
    union { u64 q[2]; bf16x8 v; } u;
    u.q[0] = lo; u.q[1] = hi;
    return u.v;
}
__device__ __forceinline__ unsigned bf16_bits(float f) {
    unsigned short s = __builtin_bit_cast(unsigned short, (bf16_t)f);
    return (unsigned)s;
}

// ---- split flag barrier (publish / wait), fence-free ----
// publish: __syncthreads drains vmcnt(0) for every wave (h stores reach LLC,
// their coherence point), then thread0 write-through-stores the stamp.
// wait: poll stamps (LLC-direct relaxed loads), then __syncthreads so no
// thread reads h before the whole block observed all producers.
// h-independent work is placed BETWEEN publish and wait to hide the round trip.
__device__ __forceinline__ void bar_publish(unsigned* arr, int idx, unsigned stamp) {
    __syncthreads();
    if (threadIdx.x == 0)
        __hip_atomic_store(&arr[idx], stamp, __ATOMIC_RELAXED, __HIP_MEMORY_SCOPE_AGENT);
}

__device__ __forceinline__ void bar_wait(unsigned* arr, int n, unsigned stamp, unsigned* flag) {
    if (threadIdx.x < (unsigned)n) {
        int spins = 0;
        while (__hip_atomic_load(&arr[threadIdx.x], __ATOMIC_RELAXED,
                                 __HIP_MEMORY_SCOPE_AGENT) < stamp) {
            if (++spins > 8) __builtin_amdgcn_s_sleep(1);   // first polls back-to-back
            if ((spins & 1023) == 0) {
                if (__hip_atomic_load(flag, __ATOMIC_RELAXED, __HIP_MEMORY_SCOPE_AGENT)) break;
                if (spins > 2000000) {  // ~0.5 s: latch diagnostic, never hang
                    __hip_atomic_fetch_or(flag, 1u, __ATOMIC_RELAXED, __HIP_MEMORY_SCOPE_AGENT);
                    break;
                }
            }
        }
    }
    __syncthreads();
}

// ---------------- small prep kernels ----------------

__global__ void cast_kernel(const float* __restrict__ src, bf16_t* __restrict__ dst, int n) {
    int i = blockIdx.x * 256 + threadIdx.x;
    if (i < n) dst[i] = (bf16_t)src[i];
}

__global__ void bias_sum_kernel(const float* __restrict__ a, const float* __restrict__ b,
                                float* __restrict__ dst, int n) {
    int i = blockIdx.x * 256 + threadIdx.x;
    if (i < n) dst[i] = a[i] + b[i];
}

// w1 [1024,64] -> w1T bf16 [64,1024]
__global__ void w1t_kernel(const float* __restrict__ w1, bf16_t* __restrict__ w1T) {
    int i = blockIdx.x * 256 + threadIdx.x;  // 65536
    int j = i >> 10, u = i & 1023;
    w1T[i] = (bf16_t)w1[u * 64 + j];
}

// cov_temp[b,t] = (b%32==31)?0 : max(0, (sum_f x^2 - (sum_f x)^2/F)/T)
__global__ __launch_bounds__(256) void cov1_kernel(const float* __restrict__ x, float* __restrict__ ct) {
    int row = blockIdx.x * 4 + (threadIdx.x >> 6);  // b*T+t
    int lane = threadIdx.x & 63;
    const float* xr = x + (size_t)row * F_;
    float s1 = 0.f, s2 = 0.f;
    for (int f = lane; f < F_; f += 64) { float v = xr[f]; s1 += v; s2 += v * v; }
    s1 = waveReduceSum(s1);
    s2 = waveReduceSum(s2);
    if (lane == 0) {
        int b = row >> 8;
        float c = (s2 - s1 * s1 * (1.f / F_)) * (1.f / T_);
        ct[row] = ((b & 31) == 31) ? 0.f : fmaxf(c, 0.f);
    }
}

// cov_chan[b,f] (bf16) = (b%32==31)?0 : max(0, (sum_t x^2 - (sum_t x)^2/T)/F)
__global__ __launch_bounds__(256) void cov2_kernel(const float* __restrict__ x,
                                                   bf16_t* __restrict__ ccb) {
    int b = blockIdx.x;
    #pragma unroll
    for (int j = 0; j < 4; ++j) {
        int f = threadIdx.x + j * 256;
        float s1 = 0.f, s2 = 0.f;
        for (int t = 0; t < T_; ++t) {
            float v = x[((size_t)b * T_ + t) * F_ + f];
            s1 += v; s2 += v * v;
        }
        float c = (s2 - s1 * s1 * (1.f / T_)) * (1.f / F_);
        if ((b & 31) == 31) c = 0.f;
        ccb[b * F_ + f] = (bf16_t)fmaxf(c, 0.f);
    }
}

// ---------------- generic MFMA GEMM: C[M,N] = A[M,K] * B[N,K]^T (+bias) ----------------
__global__ __launch_bounds__(256) void gemm_bt_kernel(
    const bf16_t* __restrict__ A, const bf16_t* __restrict__ B,
    const float* __restrict__ bias, float* __restrict__ C,
    int M, int N, int K)
{
    const int wave = threadIdx.x >> 6;
    const int lane = threadIdx.x & 63;
    const int ln15 = lane & 15;
    const int quad = lane >> 4;
    const int n_base = blockIdx.x * 64;
    const int m_wave = blockIdx.y * 128 + wave * 32;

    f32x4 acc[2][4] = {};

    int rowA0 = m_wave + ln15;       if (rowA0 >= M) rowA0 = M - 1;
    int rowA1 = m_wave + 16 + ln15;  if (rowA1 >= M) rowA1 = M - 1;
    const bf16_t* Arow0 = A + (size_t)rowA0 * K + quad * 8;
    const bf16_t* Arow1 = A + (size_t)rowA1 * K + quad * 8;
    const bf16_t* Brow0 = B + (size_t)(n_base + 0 * 16 + ln15) * K + quad * 8;
    const bf16_t* Brow1 = B + (size_t)(n_base + 1 * 16 + ln15) * K + quad * 8;
    const bf16_t* Brow2 = B + (size_t)(n_base + 2 * 16 + ln15) * K + quad * 8;
    const bf16_t* Brow3 = B + (size_t)(n_base + 3 * 16 + ln15) * K + quad * 8;

    for (int k0 = 0; k0 < K; k0 += 32) {
        bf16x8 a0 = *(const bf16x8*)(Arow0 + k0);
        bf16x8 a1 = *(const bf16x8*)(Arow1 + k0);
        bf16x8 b0 = *(const bf16x8*)(Brow0 + k0);
        bf16x8 b1 = *(const bf16x8*)(Brow1 + k0);
        bf16x8 b2 = *(const bf16x8*)(Brow2 + k0);
        bf16x8 b3 = *(const bf16x8*)(Brow3 + k0);
        acc[0][0] = MFMA16(a0, b0, acc[0][0], 0, 0, 0);
        acc[0][1] = MFMA16(a0, b1, acc[0][1], 0, 0, 0);
        acc[0][2] = MFMA16(a0, b2, acc[0][2], 0, 0, 0);
        acc[0][3] = MFMA16(a0, b3, acc[0][3], 0, 0, 0);
        acc[1][0] = MFMA16(a1, b0, acc[1][0], 0, 0, 0);
        acc[1][1] = MFMA16(a1, b1, acc[1][1], 0, 0, 0);
        acc[1][2] = MFMA16(a1, b2, acc[1][2], 0, 0, 0);
        acc[1][3] = MFMA16(a1, b3, acc[1][3], 0, 0, 0);
    }

    #pragma unroll
    for (int s = 0; s < 2; ++s) {
        #pragma unroll
        for (int g = 0; g < 4; ++g) {
            int col = n_base + g * 16 + ln15;
            float bv = bias ? bias[col] : 0.f;
            #pragma unroll
            for (int r = 0; r < 4; ++r) {
                int row = m_wave + s * 16 + quad * 4 + r;
                if (row < M) C[(size_t)row * N + col] = acc[s][g][r] + bv;
            }
        }
    }
}

// ---------------- persistent dual-LSTM recurrence ----------------
// blocks 0..127:  LSTM1, 8 units each. Per step:
//   [x-GEMM half (no h dep, overlaps others' publish)] -> wait -> [h burst-load
//   into regs, h-GEMM half, gates, h store] -> publish.
// blocks 128..191: LSTM2, 16 units each; xg2 = ct[b,t]*v[b,col] + bias2 (rank-1).
// Cross-block h exchange is fence-free: packed-u32 agent atomic stores
// (write-through to LLC), u64 agent atomic loads (LLC-direct).
__global__ __launch_bounds__(256, 1) void lstm_recur_kernel(
    const bf16_t* __restrict__ xb,    // [B,T,F] bf16
    const float*  __restrict__ ct,    // [B,T]
    const float*  __restrict__ v,     // [B,4096] fp32
    const float*  __restrict__ b1s,   // [4096]
    const float*  __restrict__ b2s,   // [4096]
    const float*  __restrict__ wih1,  // [4096,1024] fp32
    const float*  __restrict__ whh1,  // [4096,1024] fp32
    const float*  __restrict__ whh2,  // [4096,1024] fp32
    bf16_t* __restrict__ h1buf,       // [2][B][H] bf16
    bf16_t* __restrict__ h2buf,
    bf16_t* __restrict__ enc,         // [B,T,H] bf16
    float*  __restrict__ outl,        // [B,H] fp32
    unsigned* __restrict__ bar)
{
    __shared__ bf16_t wlds[64 * LPAD_];  // 132096 B

    const int blk  = blockIdx.x;
    const int is2  = (blk >= 128);
    const int wave = threadIdx.x >> 6;
    const int lane = threadIdx.x & 63;
    const int ln15 = lane & 15;
    const int quad = lane >> 4;
    const int bw   = wave * 16;

    unsigned* arr  = is2 ? (bar + 128) : bar;   // packed per-block stamp words
    const int gidx = is2 ? (blk - 128) : blk;
    const int gn   = is2 ? 64 : 128;
    unsigned* flag = bar + 224;                 // timeout diagnostic

    int u0;
    if (!is2) {
        u0 = blk * 8;
        for (int i = threadIdx.x; i < 2 * 32 * 128; i += 256) {
            int mat = i >> 12;
            int rem = i & 4095;
            int n = rem >> 7;
            int kc = (rem & 127) * 8;
            int gate = n >> 3, unit = n & 7;
            const float* src = (mat ? whh1 : wih1) + (size_t)(gate * 1024 + u0 + unit) * H_ + kc;
            float4 f0 = *(const float4*)(src);
            float4 f1 = *(const float4*)(src + 4);
            bf16x8 w;
            w[0] = (bf16_t)f0.x; w[1] = (bf16_t)f0.y; w[2] = (bf16_t)f0.z; w[3] = (bf16_t)f0.w;
            w[4] = (bf16_t)f1.x; w[5] = (bf16_t)f1.y; w[6] = (bf16_t)f1.z; w[7] = (bf16_t)f1.w;
            *(bf16x8*)&wlds[(mat * 32 + n) * LPAD_ + kc] = w;
        }
        // zero-init h1 buf0 (write-through so it's visible without fences)
        for (int i = threadIdx.x; i < 64 * 4; i += 256)
            atom_store_u32((unsigned*)h1buf + (size_t)(i >> 2) * (H_ / 2) + (u0 >> 1) + (i & 3), 0u);
    } else {
        u0 = (blk - 128) * 16;
        for (int i = threadIdx.x; i < 64 * 128; i += 256) {
            int n = i >> 7;
            int kc = (i & 127) * 8;
            int gate = n >> 4, unit = n & 15;
            const float* src = whh2 + (size_t)(gate * 1024 + u0 + unit) * H_ + kc;
            float4 f0 = *(const float4*)(src);
            float4 f1 = *(const float4*)(src + 4);
            bf16x8 w;
            w[0] = (bf16_t)f0.x; w[1] = (bf16_t)f0.y; w[2] = (bf16_t)f0.z; w[3] = (bf16_t)f0.w;
            w[4] = (bf16_t)f1.x; w[5] = (bf16_t)f1.y; w[6] = (bf16_t)f1.z; w[7] = (bf16_t)f1.w;
            *(bf16x8*)&wlds[n * LPAD_ + kc] = w;
        }
        for (int i = threadIdx.x; i < 64 * 8; i += 256)
            atom_store_u32((unsigned*)h2buf + (size_t)(i >> 3) * (H_ / 2) + (u0 >> 1) + (i & 7), 0u);
    }

    // per-thread constants
    float bias0 = 0.f, bias1 = 0.f;
    float vreg[4][4];
    float b2reg[4];
    if (!is2) {
        int col0 = (ln15 < 8) ? (u0 + ln15) : (1024 + u0 + ln15 - 8);
        int col1 = (ln15 < 8) ? (2048 + u0 + ln15) : (3072 + u0 + ln15 - 8);
        bias0 = b1s[col0];
        bias1 = b1s[col1];
    } else {
        #pragma unroll
        for (int g = 0; g < 4; ++g) {
            int colg = g * 1024 + u0 + ln15;
            b2reg[g] = b2s[colg];
            #pragma unroll
            for (int r = 0; r < 4; ++r)
                vreg[g][r] = v[(size_t)(bw + quad * 4 + r) * G4_ + colg];
        }
    }

    bar_publish(arr, gidx, 1);   // zeros + staging visible

    const bf16_t* hread  = is2 ? h2buf : h1buf;
    bf16_t*       hwrite = (is2 ? h2buf : h1buf) + B_ * H_;

    float c_st[4] = {0.f, 0.f, 0.f, 0.f};

    if (!is2) {
        unsigned stamp = 2;
        const bf16_t* xB0 = &wlds[(0 + ln15) * LPAD_ + quad * 8];
        const bf16_t* xB1 = &wlds[(16 + ln15) * LPAD_ + quad * 8];
        const bf16_t* hB0 = &wlds[(32 + ln15) * LPAD_ + quad * 8];
        const bf16_t* hB1 = &wlds[(48 + ln15) * LPAD_ + quad * 8];
        for (int t = 0; t < T_; ++t) {
            // ---- x-GEMM half: no h dependency; overlaps other blocks' publish ----
            f32x4 acc0 = {}, acc1 = {};
            const bf16_t* xA = xb + ((size_t)(bw + ln15) * T_ + t) * F_ + quad * 8;
            #pragma unroll 8
            for (int k0 = 0; k0 < H_; k0 += 32) {
                bf16x8 ax = *(const bf16x8*)(xA + k0);
                acc0 = MFMA16(ax, *(const bf16x8*)(xB0 + k0), acc0, 0, 0, 0);
                acc1 = MFMA16(ax, *(const bf16x8*)(xB1 + k0), acc1, 0, 0, 0);
            }
            // ---- h[t-1] ready? ----
            bar_wait(arr, gn, stamp - 1, flag);
            // ---- burst-load h[t-1] into registers (one LLC latency), then h-GEMM ----
            const bf16_t* hA = hread + (size_t)(bw + ln15) * H_ + quad * 8;
            bf16x8 hfrag[32];
            #pragma unroll
            for (int kk = 0; kk < 32; ++kk) hfrag[kk] = load_coh_frag(hA + kk * 32);
            #pragma unroll
            for (int kk = 0; kk < 32; ++kk) {
                acc0 = MFMA16(hfrag[kk], *(const bf16x8*)(hB0 + kk * 32), acc0, 0, 0, 0);
                acc1 = MFMA16(hfrag[kk], *(const bf16x8*)(hB1 + kk * 32), acc1, 0, 0, 0);
            }
            #pragma unroll
            for (int r = 0; r < 4; ++r) {
                int b = bw + quad * 4 + r;
                float p0 = acc0[r] + bias0;          // i (ln15<8) or f (ln15>=8)
                float p1 = acc1[r] + bias1;          // g or o
                float q0 = __shfl_xor(p0, 8);
                float q1 = __shfl_xor(p1, 8);
                float ig = (ln15 < 8) ? p0 : q0;
                float fg = (ln15 < 8) ? q0 : p0;
                float gg = (ln15 < 8) ? p1 : q1;
                float og = (ln15 < 8) ? q1 : p1;
                ig = sig_fast(ig); fg = sig_fast(fg);
                gg = tanh_fast(gg); og = sig_fast(og);
                float c = fg * c_st[r] + ig * gg;
                c_st[r] = c;
                float h = og * tanh_fast(c);
                unsigned hv = bf16_bits(h);
                unsigned pv = __shfl_xor(hv, 1);     // partner unit's h (ln15 xor 1)
                if ((ln15 & 1) == 0 && ln15 < 8)
                    atom_store_u32((unsigned*)hwrite + (size_t)b * (H_ / 2) + ((u0 + ln15) >> 1),
                                   hv | (pv << 16));
                if (ln15 < 8 && t == T_ - 1) outl[(size_t)b * H_ + u0 + ln15] = h;
            }
            bar_publish(arr, gidx, stamp);
            stamp++;
            bf16_t* tmp = (bf16_t*)hread; hread = hwrite; hwrite = tmp;
        }
    } else {
        unsigned stamp = 2;
        const bf16_t* B0 = &wlds[(0 * 16 + ln15) * LPAD_ + quad * 8];
        const bf16_t* B1 = &wlds[(1 * 16 + ln15) * LPAD_ + quad * 8];
        const bf16_t* B2 = &wlds[(2 * 16 + ln15) * LPAD_ + quad * 8];
        const bf16_t* B3 = &wlds[(3 * 16 + ln15) * LPAD_ + quad * 8];
        for (int t = 0; t < T_; ++t) {
            bar_wait(arr, gn, stamp - 1, flag);
            const bf16_t* hA = hread + (size_t)(bw + ln15) * H_ + quad * 8;
            bf16x8 hfrag[32];
            #pragma unroll
            for (int kk = 0; kk < 32; ++kk) hfrag[kk] = load_coh_frag(hA + kk * 32);
            f32x4 acc[4] = {};
            #pragma unroll
            for (int kk = 0; kk < 32; ++kk) {
                acc[0] = MFMA16(hfrag[kk], *(const bf16x8*)(B0 + kk * 32), acc[0], 0, 0, 0);
                acc[1] = MFMA16(hfrag[kk], *(const bf16x8*)(B1 + kk * 32), acc[1], 0, 0, 0);
                acc[2] = MFMA16(hfrag[kk], *(const bf16x8*)(B2 + kk * 32), acc[2], 0, 0, 0);
                acc[3] = MFMA16(hfrag[kk], *(const bf16x8*)(B3 + kk * 32), acc[3], 0, 0, 0);
            }
            #pragma unroll
            for (int r = 0; r < 4; ++r) {
                int b = bw + quad * 4 + r;
                float cts = ct[b * T_ + t];
                float ig = sig_fast(acc[0][r] + cts * vreg[0][r] + b2reg[0]);
                float fg = sig_fast(acc[1][r] + cts * vreg[1][r] + b2reg[1]);
                float gg = tanh_fast(acc[2][r] + cts * vreg[2][r] + b2reg[2]);
                float og = sig_fast(acc[3][r] + cts * vreg[3][r] + b2reg[3]);
                float c = fg * c_st[r] + ig * gg;
                c_st[r] = c;
                float h = og * tanh_fast(c);
                unsigned hv = bf16_bits(h);
                unsigned pv = __shfl_xor(hv, 1);
                if ((ln15 & 1) == 0) {
                    unsigned word = hv | (pv << 16);
                    atom_store_u32((unsigned*)hwrite + (size_t)b * (H_ / 2) + ((u0 + ln15) >> 1), word);
                    // enc is consumed only after kernel end -> normal (dirty-L2) store is fine
                    *((unsigned*)enc + ((size_t)b * T_ + t) * (H_ / 2) + ((u0 + ln15) >> 1)) = word;
                }
            }
            bar_publish(arr, gidx, stamp);
            stamp++;
            bf16_t* tmp = (bf16_t*)hread; hread = hwrite; hwrite = tmp;
        }
    }
}

// ---------------- attention epilogue ----------------

__global__ __launch_bounds__(256) void p1_kernel(const bf16_t* __restrict__ enc,
                                                 float* __restrict__ Msm, float* __restrict__ Ssm) {
    int b = blockIdx.x;
    #pragma unroll
    for (int j = 0; j < 4; ++j) {
        int u = threadIdx.x + j * 256;
        const bf16_t* e = enc + (size_t)b * T_ * H_ + u;
        float m = -1e30f;
        for (int t = 0; t < T_; ++t) m = fmaxf(m, (float)e[(size_t)t * H_]);
        float s = 0.f;
        for (int t = 0; t < T_; ++t) s += __expf((float)e[(size_t)t * H_] - m);
        Msm[b * H_ + u] = m;
        Ssm[b * H_ + u] = s;
    }
}

__global__ __launch_bounds__(256) void p2_kernel(
    const bf16_t* __restrict__ enc, const float* __restrict__ Msm, const float* __restrict__ Ssm,
    const float* __restrict__ outl, const float* __restrict__ w_attn,
    bf16_t* __restrict__ saa, float* __restrict__ tapre) {
    int row = blockIdx.x;   // b*T+t
    int b = row >> 8;
    const bf16_t* erow = enc + (size_t)row * H_;
    float tsum = 0.f;
    for (int u = threadIdx.x; u < H_; u += 256) {
        float e = (float)erow[u];
        float sp = __expf(e - Msm[b * H_ + u]) / Ssm[b * H_ + u];
        saa[(size_t)row * H_ + u] = (bf16_t)(outl[b * H_ + u] * (sp + 1.f));
        tsum += tanh_fast(e) * w_attn[u];
    }
    tsum = waveReduceSum(tsum);
    __shared__ float red[4];
    if ((threadIdx.x & 63) == 0) red[threadIdx.x >> 6] = tsum;
    __syncthreads();
    if (threadIdx.x == 0) tapre[row] = red[0] + red[1] + red[2] + red[3];
}

// final: det = sigmoid(relu(r1)@w2 + b2); out = det*(1+sigmoid(tapre+b_attn))  [fp32 out]
__global__ __launch_bounds__(256) void p4_kernel(
    const float* __restrict__ r1, const float* __restrict__ w2, const float* __restrict__ b2,
    const float* __restrict__ tapre, const float* __restrict__ b_attn,
    const unsigned* __restrict__ flag, float* __restrict__ out) {
    int row = blockIdx.x * 4 + (threadIdx.x >> 6);
    int lane = threadIdx.x & 63;
    float vsum = fmaxf(r1[(size_t)row * 64 + lane], 0.f) * w2[lane];
    vsum = waveReduceSum(vsum);
    if (lane == 0) {
        float det = sig_fast(vsum + b2[0]);
        float ta = sig_fast(tapre[row] + b_attn[0]);
        out[row] = det * (1.f + ta) + 1000.f * (float)(*flag);
    }
}

// ---------------- launcher ----------------

extern "C" void kernel_launch(void* const* d_in, const int* in_sizes, int n_in,
                              void* d_out, int out_size, void* d_ws, size_t ws_size,
                              hipStream_t stream) {
    const float* x      = (const float*)d_in[0];
    const float* W_ih1  = (const float*)d_in[1];
    const float* W_hh1  = (const float*)d_in[2];
    const float* b_ih1  = (const float*)d_in[3];
    const float* b_hh1  = (const float*)d_in[4];
    const float* W_ih2  = (const float*)d_in[5];
    const float* W_hh2  = (const float*)d_in[6];
    const float* b_ih2  = (const float*)d_in[7];
    const float* b_hh2  = (const float*)d_in[8];
    const float* w_attn = (const float*)d_in[9];
    const float* b_attn = (const float*)d_in[10];
    const float* w1     = (const float*)d_in[11];
    const float* b1     = (const float*)d_in[12];
    const float* w2     = (const float*)d_in[13];
    const float* b2     = (const float*)d_in[14];

    char* ws = (char*)d_ws;
    size_t off = 0;
    auto alloc = [&](size_t bytes) { size_t r = off; off = (off + bytes + 255) & ~(size_t)255; return r; };

    size_t o_bar  = alloc(1024);                      // 128+64 flags + diag flag
    size_t o_wih2 = alloc((size_t)G4_ * H_ * 2);      // 8 MB bf16 (for v-gemm)
    size_t o_xb   = alloc((size_t)B_ * T_ * F_ * 2);  // 32 MB
    size_t o_b1s  = alloc(G4_ * 4);
    size_t o_b2s  = alloc(G4_ * 4);
    size_t o_ct   = alloc(B_ * T_ * 4);
    size_t o_ccb  = alloc(B_ * F_ * 2);
    size_t o_v    = alloc((size_t)B_ * G4_ * 4);      // 1 MB
    size_t o_h1   = alloc(2 * B_ * H_ * 2);
    size_t o_h2   = alloc(2 * B_ * H_ * 2);
    size_t o_outl = alloc(B_ * H_ * 4);
    size_t o_w1t  = alloc(64 * H_ * 2);
    size_t o_msm  = alloc(B_ * H_ * 4);
    size_t o_ssm  = alloc(B_ * H_ * 4);
    size_t o_tap  = alloc(B_ * T_ * 4);
    size_t o_enc  = alloc((size_t)B_ * T_ * H_ * 2);  // 32 MB bf16
    size_t o_saa  = o_xb;                             // alias: xb dead after recurrence
    size_t o_r1   = o_enc;                            // alias: enc dead after p2

    if (ws_size < off) return;  // fail loudly as absmax mismatch, never a fault

    unsigned* bar  = (unsigned*)(ws + o_bar);
    bf16_t* wih2b  = (bf16_t*)(ws + o_wih2);
    bf16_t* xb     = (bf16_t*)(ws + o_xb);
    float*  b1s    = (float*)(ws + o_b1s);
    float*  b2s    = (float*)(ws + o_b2s);
    float*  ctp    = (float*)(ws + o_ct);
    bf16_t* ccb    = (bf16_t*)(ws + o_ccb);
    float*  vbuf   = (float*)(ws + o_v);
    bf16_t* h1     = (bf16_t*)(ws + o_h1);
    bf16_t* h2     = (bf16_t*)(ws + o_h2);
    float*  outl   = (float*)(ws + o_outl);
    bf16_t* w1t    = (bf16_t*)(ws + o_w1t);
    float*  msm    = (float*)(ws + o_msm);
    float*  ssm    = (float*)(ws + o_ssm);
    float*  tap    = (float*)(ws + o_tap);
    bf16_t* encp   = (bf16_t*)(ws + o_enc);
    bf16_t* saa    = (bf16_t*)(ws + o_saa);
    float*  r1     = (float*)(ws + o_r1);

    hipMemsetAsync(ws + o_bar, 0, 1024, stream);

    int n = G4_ * H_;
    cast_kernel<<<(n + 255) / 256, 256, 0, stream>>>(W_ih2, wih2b, n);
    n = B_ * T_ * F_;
    cast_kernel<<<(n + 255) / 256, 256, 0, stream>>>(x, xb, n);
    bias_sum_kernel<<<16, 256, 0, stream>>>(b_ih1, b_hh1, b1s, G4_);
    bias_sum_kernel<<<16, 256, 0, stream>>>(b_ih2, b_hh2, b2s, G4_);
    cov1_kernel<<<B_ * T_ / 4, 256, 0, stream>>>(x, ctp);
    cov2_kernel<<<B_, 256, 0, stream>>>(x, ccb);
    w1t_kernel<<<256, 256, 0, stream>>>(w1, w1t);

    // v = cov_chan * Wih2^T (fp32 out)
    gemm_bt_kernel<<<dim3(G4_ / 64, 1), 256, 0, stream>>>(ccb, wih2b, nullptr, vbuf, B_, G4_, H_);

    lstm_recur_kernel<<<NBLK_, 256, 0, stream>>>(
        xb, ctp, vbuf, b1s, b2s, W_ih1, W_hh1, W_hh2, h1, h2, encp, outl, bar);

    p1_kernel<<<B_, 256, 0, stream>>>(encp, msm, ssm);
    p2_kernel<<<B_ * T_, 256, 0, stream>>>(encp, msm, ssm, outl, w_attn, saa, tap);
    // r1 = saa * w1T^T + b1 (fp32 out)
    gemm_bt_kernel<<<dim3(1, B_ * T_ / 128), 256, 0, stream>>>(saa, w1t, b1, r1, B_ * T_, 64, H_);
    p4_kernel<<<B_ * T_ / 4, 256, 0, stream>>>(r1, w2, b2, tap, b_attn, bar + 224, (float*)d_out);

    (void)in_sizes; (void)n_in; (void)out_size;
}

// Round 3
// 3827.574 us; speedup vs baseline: 1.4679x; 1.1812x over previous
//
#include <hip/hip_runtime.h>

typedef __bf16 bf16_t;
typedef __bf16 bf16x8 __attribute__((ext_vector_type(8)));
typedef float f32x4 __attribute__((ext_vector_type(4)));
typedef unsigned long long u64;

#define B_ 64
#define T_ 256
#define F_ 1024
#define H_ 1024
#define G4_ 4096
#define NBLK_ 192
#define LPAD_ 1032   // row stride (elems): 2064B = 16B-aligned, worst 2-way LDS conflict (free)

#define MFMA16 __builtin_amdgcn_mfma_f32_16x16x32_bf16

__device__ __forceinline__ float sig_fast(float x) { return 1.f / (1.f + __expf(-x)); }
__device__ __forceinline__ float tanh_fast(float x) {
    float e = __expf(2.f * x);
    return 1.f - 2.f / (e + 1.f);
}
__device__ __forceinline__ float waveReduceSum(float v) {
    #pragma unroll
    for (int off = 32; off > 0; off >>= 1) v += __shfl_xor(v, off);
    return v;
}

// ---- agent-coherent (sc0 sc1) helpers: per-instruction coherence, NO cache fences ----
__device__ __forceinline__ void atom_store_u32(unsigned* p, unsigned v) {
    __hip_atomic_store(p, v, __ATOMIC_RELAXED, __HIP_MEMORY_SCOPE_AGENT);
}
// 16B h-fragment read that bypasses (possibly stale) L1/L2 and reads the LLC.
__device__ __forceinline__ bf16x8 load_coh_frag(const bf16_t* p) {
    u64 lo = __hip_atomic_load((u64*)p,     __ATOMIC_RELAXED, __HIP_MEMORY_SCOPE_AGENT);
    u64 hi = __hip_atomic_load((u64*)p + 1, __ATOMIC_RELAXED, __HIP_MEMORY_SCOPE_AGENT);
    union { u64 q[2]; bf16x8 v; } u;
    u.q[0] = lo; u.q[1] = hi;
    return u.v;
}
__device__ __forceinline__ unsigned bf16_bits(float f) {
    unsigned short s = __builtin_bit_cast(unsigned short, (bf16_t)f);
    return (unsigned)s;
}

// ---- split flag barrier (publish / wait), fence-free ----
// publish: __syncthreads drains vmcnt(0) for every wave (h stores reach LLC,
// their coherence point), then thread0 write-through-stores the stamp.
// wait: BUSY-poll stamps (LLC-direct relaxed loads; no s_sleep — shortest
// discovery latency and keeps the clock up), then __syncthreads.
__device__ __forceinline__ void bar_publish(unsigned* arr, int idx, unsigned stamp) {
    __syncthreads();
    if (threadIdx.x == 0)
        __hip_atomic_store(&arr[idx], stamp, __ATOMIC_RELAXED, __HIP_MEMORY_SCOPE_AGENT);
}

__device__ __forceinline__ void bar_wait(unsigned* arr, int n, unsigned stamp, unsigned* flag) {
    if (threadIdx.x < (unsigned)n) {
        int spins = 0;
        while (__hip_atomic_load(&arr[threadIdx.x], __ATOMIC_RELAXED,
                                 __HIP_MEMORY_SCOPE_AGENT) < stamp) {
            if ((++spins & 2047) == 0) {
                if (__hip_atomic_load(flag, __ATOMIC_RELAXED, __HIP_MEMORY_SCOPE_AGENT)) break;
                if (spins > 4000000) {  // ~1 s of busy polls: latch diagnostic, never hang
                    __hip_atomic_fetch_or(flag, 1u, __ATOMIC_RELAXED, __HIP_MEMORY_SCOPE_AGENT);
                    break;
                }
            }
        }
    }
    __syncthreads();
}

// ---------------- small prep kernels ----------------

__global__ void cast_kernel(const float* __restrict__ src, bf16_t* __restrict__ dst, int n) {
    int i = blockIdx.x * 256 + threadIdx.x;
    if (i < n) dst[i] = (bf16_t)src[i];
}

__global__ void bias_sum_kernel(const float* __restrict__ a, const float* __restrict__ b,
                                float* __restrict__ dst, int n) {
    int i = blockIdx.x * 256 + threadIdx.x;
    if (i < n) dst[i] = a[i] + b[i];
}

// w1 [1024,64] -> w1T bf16 [64,1024]
__global__ void w1t_kernel(const float* __restrict__ w1, bf16_t* __restrict__ w1T) {
    int i = blockIdx.x * 256 + threadIdx.x;  // 65536
    int j = i >> 10, u = i & 1023;
    w1T[i] = (bf16_t)w1[u * 64 + j];
}

// cov_temp[b,t] = (b%32==31)?0 : max(0, (sum_f x^2 - (sum_f x)^2/F)/T)
__global__ __launch_bounds__(256) void cov1_kernel(const float* __restrict__ x, float* __restrict__ ct) {
    int row = blockIdx.x * 4 + (threadIdx.x >> 6);  // b*T+t
    int lane = threadIdx.x & 63;
    const float* xr = x + (size_t)row * F_;
    float s1 = 0.f, s2 = 0.f;
    for (int f = lane; f < F_; f += 64) { float v = xr[f]; s1 += v; s2 += v * v; }
    s1 = waveReduceSum(s1);
    s2 = waveReduceSum(s2);
    if (lane == 0) {
        int b = row >> 8;
        float c = (s2 - s1 * s1 * (1.f / F_)) * (1.f / T_);
        ct[row] = ((b & 31) == 31) ? 0.f : fmaxf(c, 0.f);
    }
}

// cov_chan[b,f] (bf16) = (b%32==31)?0 : max(0, (sum_t x^2 - (sum_t x)^2/T)/F)
__global__ __launch_bounds__(256) void cov2_kernel(const float* __restrict__ x,
                                                   bf16_t* __restrict__ ccb) {
    int b = blockIdx.x;
    #pragma unroll
    for (int j = 0; j < 4; ++j) {
        int f = threadIdx.x + j * 256;
        float s1 = 0.f, s2 = 0.f;
        for (int t = 0; t < T_; ++t) {
            float v = x[((size_t)b * T_ + t) * F_ + f];
            s1 += v; s2 += v * v;
        }
        float c = (s2 - s1 * s1 * (1.f / T_)) * (1.f / F_);
        if ((b & 31) == 31) c = 0.f;
        ccb[b * F_ + f] = (bf16_t)fmaxf(c, 0.f);
    }
}

// ---------------- generic MFMA GEMM: C[M,N] = A[M,K] * B[N,K]^T (+bias) ----------------
__global__ __launch_bounds__(256) void gemm_bt_kernel(
    const bf16_t* __restrict__ A, const bf16_t* __restrict__ B,
    const float* __restrict__ bias, float* __restrict__ C,
    int M, int N, int K)
{
    const int wave = threadIdx.x >> 6;
    const int lane = threadIdx.x & 63;
    const int ln15 = lane & 15;
    const int quad = lane >> 4;
    const int n_base = blockIdx.x * 64;
    const int m_wave = blockIdx.y * 128 + wave * 32;

    f32x4 acc[2][4] = {};

    int rowA0 = m_wave + ln15;       if (rowA0 >= M) rowA0 = M - 1;
    int rowA1 = m_wave + 16 + ln15;  if (rowA1 >= M) rowA1 = M - 1;
    const bf16_t* Arow0 = A + (size_t)rowA0 * K + quad * 8;
    const bf16_t* Arow1 = A + (size_t)rowA1 * K + quad * 8;
    const bf16_t* Brow0 = B + (size_t)(n_base + 0 * 16 + ln15) * K + quad * 8;
    const bf16_t* Brow1 = B + (size_t)(n_base + 1 * 16 + ln15) * K + quad * 8;
    const bf16_t* Brow2 = B + (size_t)(n_base + 2 * 16 + ln15) * K + quad * 8;
    const bf16_t* Brow3 = B + (size_t)(n_base + 3 * 16 + ln15) * K + quad * 8;

    for (int k0 = 0; k0 < K; k0 += 32) {
        bf16x8 a0 = *(const bf16x8*)(Arow0 + k0);
        bf16x8 a1 = *(const bf16x8*)(Arow1 + k0);
        bf16x8 b0 = *(const bf16x8*)(Brow0 + k0);
        bf16x8 b1 = *(const bf16x8*)(Brow1 + k0);
        bf16x8 b2 = *(const bf16x8*)(Brow2 + k0);
        bf16x8 b3 = *(const bf16x8*)(Brow3 + k0);
        acc[0][0] = MFMA16(a0, b0, acc[0][0], 0, 0, 0);
        acc[0][1] = MFMA16(a0, b1, acc[0][1], 0, 0, 0);
        acc[0][2] = MFMA16(a0, b2, acc[0][2], 0, 0, 0);
        acc[0][3] = MFMA16(a0, b3, acc[0][3], 0, 0, 0);
        acc[1][0] = MFMA16(a1, b0, acc[1][0], 0, 0, 0);
        acc[1][1] = MFMA16(a1, b1, acc[1][1], 0, 0, 0);
        acc[1][2] = MFMA16(a1, b2, acc[1][2], 0, 0, 0);
        acc[1][3] = MFMA16(a1, b3, acc[1][3], 0, 0, 0);
    }

    #pragma unroll
    for (int s = 0; s < 2; ++s) {
        #pragma unroll
        for (int g = 0; g < 4; ++g) {
            int col = n_base + g * 16 + ln15;
            float bv = bias ? bias[col] : 0.f;
            #pragma unroll
            for (int r = 0; r < 4; ++r) {
                int row = m_wave + s * 16 + quad * 4 + r;
                if (row < M) C[(size_t)row * N + col] = acc[s][g][r] + bv;
            }
        }
    }
}

// ---------------- persistent dual-LSTM recurrence ----------------
// blocks 0..127:  LSTM1, 8 units each. Per step:
//   [burst x loads | SCHED_BARRIER | x-MFMAs]  (overlaps others' publish)
//   -> wait -> [burst h loads | SCHED_BARRIER | h-MFMAs] -> gates -> publish.
// blocks 128..191: LSTM2, 16 units each; xg2 = ct[b,t]*v[b,col] + bias2 (rank-1).
// sched_barrier(0) pins ALL fragment loads before ANY consumer, forcing the
// full burst into flight (one memory latency per phase, ~128 live VGPRs)
// instead of the compiler's register-saving serialized dribble.
__global__ __launch_bounds__(256, 1) void lstm_recur_kernel(
    const bf16_t* __restrict__ xb,    // [B,T,F] bf16
    const float*  __restrict__ ct,    // [B,T]
    const float*  __restrict__ v,     // [B,4096] fp32
    const float*  __restrict__ b1s,   // [4096]
    const float*  __restrict__ b2s,   // [4096]
    const float*  __restrict__ wih1,  // [4096,1024] fp32
    const float*  __restrict__ whh1,  // [4096,1024] fp32
    const float*  __restrict__ whh2,  // [4096,1024] fp32
    bf16_t* __restrict__ h1buf,       // [2][B][H] bf16
    bf16_t* __restrict__ h2buf,
    bf16_t* __restrict__ enc,         // [B,T,H] bf16
    float*  __restrict__ outl,        // [B,H] fp32
    unsigned* __restrict__ bar)
{
    __shared__ bf16_t wlds[64 * LPAD_];  // 132096 B

    const int blk  = blockIdx.x;
    const int is2  = (blk >= 128);
    const int wave = threadIdx.x >> 6;
    const int lane = threadIdx.x & 63;
    const int ln15 = lane & 15;
    const int quad = lane >> 4;
    const int bw   = wave * 16;

    unsigned* arr  = is2 ? (bar + 128) : bar;   // packed per-block stamp words
    const int gidx = is2 ? (blk - 128) : blk;
    const int gn   = is2 ? 64 : 128;
    unsigned* flag = bar + 224;                 // timeout diagnostic

    int u0;
    if (!is2) {
        u0 = blk * 8;
        for (int i = threadIdx.x; i < 2 * 32 * 128; i += 256) {
            int mat = i >> 12;
            int rem = i & 4095;
            int n = rem >> 7;
            int kc = (rem & 127) * 8;
            int gate = n >> 3, unit = n & 7;
            const float* src = (mat ? whh1 : wih1) + (size_t)(gate * 1024 + u0 + unit) * H_ + kc;
            float4 f0 = *(const float4*)(src);
            float4 f1 = *(const float4*)(src + 4);
            bf16x8 w;
            w[0] = (bf16_t)f0.x; w[1] = (bf16_t)f0.y; w[2] = (bf16_t)f0.z; w[3] = (bf16_t)f0.w;
            w[4] = (bf16_t)f1.x; w[5] = (bf16_t)f1.y; w[6] = (bf16_t)f1.z; w[7] = (bf16_t)f1.w;
            *(bf16x8*)&wlds[(mat * 32 + n) * LPAD_ + kc] = w;
        }
        // zero-init h1 buf0 (write-through so it's visible without fences)
        for (int i = threadIdx.x; i < 64 * 4; i += 256)
            atom_store_u32((unsigned*)h1buf + (size_t)(i >> 2) * (H_ / 2) + (u0 >> 1) + (i & 3), 0u);
    } else {
        u0 = (blk - 128) * 16;
        for (int i = threadIdx.x; i < 64 * 128; i += 256) {
            int n = i >> 7;
            int kc = (i & 127) * 8;
            int gate = n >> 4, unit = n & 15;
            const float* src = whh2 + (size_t)(gate * 1024 + u0 + unit) * H_ + kc;
            float4 f0 = *(const float4*)(src);
            float4 f1 = *(const float4*)(src + 4);
            bf16x8 w;
            w[0] = (bf16_t)f0.x; w[1] = (bf16_t)f0.y; w[2] = (bf16_t)f0.z; w[3] = (bf16_t)f0.w;
            w[4] = (bf16_t)f1.x; w[5] = (bf16_t)f1.y; w[6] = (bf16_t)f1.z; w[7] = (bf16_t)f1.w;
            *(bf16x8*)&wlds[n * LPAD_ + kc] = w;
        }
        for (int i = threadIdx.x; i < 64 * 8; i += 256)
            atom_store_u32((unsigned*)h2buf + (size_t)(i >> 3) * (H_ / 2) + (u0 >> 1) + (i & 7), 0u);
    }

    // per-thread constants
    float bias0 = 0.f, bias1 = 0.f;
    float vreg[4][4];
    float b2reg[4];
    if (!is2) {
        int col0 = (ln15 < 8) ? (u0 + ln15) : (1024 + u0 + ln15 - 8);
        int col1 = (ln15 < 8) ? (2048 + u0 + ln15) : (3072 + u0 + ln15 - 8);
        bias0 = b1s[col0];
        bias1 = b1s[col1];
    } else {
        #pragma unroll
        for (int g = 0; g < 4; ++g) {
            int colg = g * 1024 + u0 + ln15;
            b2reg[g] = b2s[colg];
            #pragma unroll
            for (int r = 0; r < 4; ++r)
                vreg[g][r] = v[(size_t)(bw + quad * 4 + r) * G4_ + colg];
        }
    }

    bar_publish(arr, gidx, 1);   // zeros + staging visible

    const bf16_t* hread  = is2 ? h2buf : h1buf;
    bf16_t*       hwrite = (is2 ? h2buf : h1buf) + B_ * H_;

    float c_st[4] = {0.f, 0.f, 0.f, 0.f};

    if (!is2) {
        unsigned stamp = 2;
        const bf16_t* xB0 = &wlds[(0 + ln15) * LPAD_ + quad * 8];
        const bf16_t* xB1 = &wlds[(16 + ln15) * LPAD_ + quad * 8];
        const bf16_t* hB0 = &wlds[(32 + ln15) * LPAD_ + quad * 8];
        const bf16_t* hB1 = &wlds[(48 + ln15) * LPAD_ + quad * 8];
        for (int t = 0; t < T_; ++t) {
            // ---- burst-issue ALL x frags (one memory latency), pin with sched_barrier ----
            const bf16_t* xA = xb + ((size_t)(bw + ln15) * T_ + t) * F_ + quad * 8;
            bf16x8 xfrag[32];
            #pragma unroll
            for (int kk = 0; kk < 32; ++kk) xfrag[kk] = *(const bf16x8*)(xA + kk * 32);
            __builtin_amdgcn_sched_barrier(0);
            // ---- x-MFMAs: no h dependency; overlaps other blocks' publish ----
            f32x4 acc0 = {}, acc1 = {};
            #pragma unroll
            for (int kk = 0; kk < 32; ++kk) {
                acc0 = MFMA16(xfrag[kk], *(const bf16x8*)(xB0 + kk * 32), acc0, 0, 0, 0);
                acc1 = MFMA16(xfrag[kk], *(const bf16x8*)(xB1 + kk * 32), acc1, 0, 0, 0);
            }
            // ---- h[t-1] ready? ----
            bar_wait(arr, gn, stamp - 1, flag);
            // ---- burst-load h[t-1] (one LLC latency), then h-GEMM ----
            const bf16_t* hA = hread + (size_t)(bw + ln15) * H_ + quad * 8;
            bf16x8 hfrag[32];
            #pragma unroll
            for (int kk = 0; kk < 32; ++kk) hfrag[kk] = load_coh_frag(hA + kk * 32);
            __builtin_amdgcn_sched_barrier(0);
            #pragma unroll
            for (int kk = 0; kk < 32; ++kk) {
                acc0 = MFMA16(hfrag[kk], *(const bf16x8*)(hB0 + kk * 32), acc0, 0, 0, 0);
                acc1 = MFMA16(hfrag[kk], *(const bf16x8*)(hB1 + kk * 32), acc1, 0, 0, 0);
            }
            #pragma unroll
            for (int r = 0; r < 4; ++r) {
                int b = bw + quad * 4 + r;
                float p0 = acc0[r] + bias0;          // i (ln15<8) or f (ln15>=8)
                float p1 = acc1[r] + bias1;          // g or o
                float q0 = __shfl_xor(p0, 8);
                float q1 = __shfl_xor(p1, 8);
                float ig = (ln15 < 8) ? p0 : q0;
                float fg = (ln15 < 8) ? q0 : p0;
                float gg = (ln15 < 8) ? p1 : q1;
                float og = (ln15 < 8) ? q1 : p1;
                ig = sig_fast(ig); fg = sig_fast(fg);
                gg = tanh_fast(gg); og = sig_fast(og);
                float c = fg * c_st[r] + ig * gg;
                c_st[r] = c;
                float h = og * tanh_fast(c);
                unsigned hv = bf16_bits(h);
                unsigned pv = __shfl_xor(hv, 1);     // partner unit's h (ln15 xor 1)
                if ((ln15 & 1) == 0 && ln15 < 8)
                    atom_store_u32((unsigned*)hwrite + (size_t)b * (H_ / 2) + ((u0 + ln15) >> 1),
                                   hv | (pv << 16));
                if (ln15 < 8 && t == T_ - 1) outl[(size_t)b * H_ + u0 + ln15] = h;
            }
            bar_publish(arr, gidx, stamp);
            stamp++;
            bf16_t* tmp = (bf16_t*)hread; hread = hwrite; hwrite = tmp;
        }
    } else {
        unsigned stamp = 2;
        const bf16_t* B0 = &wlds[(0 * 16 + ln15) * LPAD_ + quad * 8];
        const bf16_t* B1 = &wlds[(1 * 16 + ln15) * LPAD_ + quad * 8];
        const bf16_t* B2 = &wlds[(2 * 16 + ln15) * LPAD_ + quad * 8];
        const bf16_t* B3 = &wlds[(3 * 16 + ln15) * LPAD_ + quad * 8];
        for (int t = 0; t < T_; ++t) {
            // prefetch this step's ct scalars before the wait (cached loads)
            float cts_r[4];
            #pragma unroll
            for (int r = 0; r < 4; ++r) cts_r[r] = ct[(bw + quad * 4 + r) * T_ + t];
            bar_wait(arr, gn, stamp - 1, flag);
            // ---- burst-load h[t-1] (one LLC latency), pin, then h-GEMM ----
            const bf16_t* hA = hread + (size_t)(bw + ln15) * H_ + quad * 8;
            bf16x8 hfrag[32];
            #pragma unroll
            for (int kk = 0; kk < 32; ++kk) hfrag[kk] = load_coh_frag(hA + kk * 32);
            __builtin_amdgcn_sched_barrier(0);
            f32x4 acc[4] = {};
            #pragma unroll
            for (int kk = 0; kk < 32; ++kk) {
                acc[0] = MFMA16(hfrag[kk], *(const bf16x8*)(B0 + kk * 32), acc[0], 0, 0, 0);
                acc[1] = MFMA16(hfrag[kk], *(const bf16x8*)(B1 + kk * 32), acc[1], 0, 0, 0);
                acc[2] = MFMA16(hfrag[kk], *(const bf16x8*)(B2 + kk * 32), acc[2], 0, 0, 0);
                acc[3] = MFMA16(hfrag[kk], *(const bf16x8*)(B3 + kk * 32), acc[3], 0, 0, 0);
            }
            #pragma unroll
            for (int r = 0; r < 4; ++r) {
                int b = bw + quad * 4 + r;
                float cts = cts_r[r];
                float ig = sig_fast(acc[0][r] + cts * vreg[0][r] + b2reg[0]);
                float fg = sig_fast(acc[1][r] + cts * vreg[1][r] + b2reg[1]);
                float gg = tanh_fast(acc[2][r] + cts * vreg[2][r] + b2reg[2]);
                float og = sig_fast(acc[3][r] + cts * vreg[3][r] + b2reg[3]);
                float c = fg * c_st[r] + ig * gg;
                c_st[r] = c;
                float h = og * tanh_fast(c);
                unsigned hv = bf16_bits(h);
                unsigned pv = __shfl_xor(hv, 1);
                if ((ln15 & 1) == 0) {
                    unsigned word = hv | (pv << 16);
                    atom_store_u32((unsigned*)hwrite + (size_t)b * (H_ / 2) + ((u0 + ln15) >> 1), word);
                    // enc is consumed only after kernel end -> normal (dirty-L2) store is fine
                    *((unsigned*)enc + ((size_t)b * T_ + t) * (H_ / 2) + ((u0 + ln15) >> 1)) = word;
                }
            }
            bar_publish(arr, gidx, stamp);
            stamp++;
            bf16_t* tmp = (bf16_t*)hread; hread = hwrite; hwrite = tmp;
        }
    }
}

// ---------------- attention epilogue ----------------

__global__ __launch_bounds__(256) void p1_kernel(const bf16_t* __restrict__ enc,
                                                 float* __restrict__ Msm, float* __restrict__ Ssm) {
    int b = blockIdx.x;
    #pragma unroll
    for (int j = 0; j < 4; ++j) {
        int u = threadIdx.x + j * 256;
        const bf16_t* e = enc + (size_t)b * T_ * H_ + u;
        float m = -1e30f;
        for (int t = 0; t < T_; ++t) m = fmaxf(m, (float)e[(size_t)t * H_]);
        float s = 0.f;
        for (int t = 0; t < T_; ++t) s += __expf((float)e[(size_t)t * H_] - m);
        Msm[b * H_ + u] = m;
        Ssm[b * H_ + u] = s;
    }
}

__global__ __launch_bounds__(256) void p2_kernel(
    const bf16_t* __restrict__ enc, const float* __restrict__ Msm, const float* __restrict__ Ssm,
    const float* __restrict__ outl, const float* __restrict__ w_attn,
    bf16_t* __restrict__ saa, float* __restrict__ tapre) {
    int row = blockIdx.x;   // b*T+t
    int b = row >> 8;
    const bf16_t* erow = enc + (size_t)row * H_;
    float tsum = 0.f;
    for (int u = threadIdx.x; u < H_; u += 256) {
        float e = (float)erow[u];
        float sp = __expf(e - Msm[b * H_ + u]) / Ssm[b * H_ + u];
        saa[(size_t)row * H_ + u] = (bf16_t)(outl[b * H_ + u] * (sp + 1.f));
        tsum += tanh_fast(e) * w_attn[u];
    }
    tsum = waveReduceSum(tsum);
    __shared__ float red[4];
    if ((threadIdx.x & 63) == 0) red[threadIdx.x >> 6] = tsum;
    __syncthreads();
    if (threadIdx.x == 0) tapre[row] = red[0] + red[1] + red[2] + red[3];
}

// final: det = sigmoid(relu(r1)@w2 + b2); out = det*(1+sigmoid(tapre+b_attn))  [fp32 out]
__global__ __launch_bounds__(256) void p4_kernel(
    const float* __restrict__ r1, const float* __restrict__ w2, const float* __restrict__ b2,
    const float* __restrict__ tapre, const float* __restrict__ b_attn,
    const unsigned* __restrict__ flag, float* __restrict__ out) {
    int row = blockIdx.x * 4 + (threadIdx.x >> 6);
    int lane = threadIdx.x & 63;
    float vsum = fmaxf(r1[(size_t)row * 64 + lane], 0.f) * w2[lane];
    vsum = waveReduceSum(vsum);
    if (lane == 0) {
        float det = sig_fast(vsum + b2[0]);
        float ta = sig_fast(tapre[row] + b_attn[0]);
        out[row] = det * (1.f + ta) + 1000.f * (float)(*flag);
    }
}

// ---------------- launcher ----------------

extern "C" void kernel_launch(void* const* d_in, const int* in_sizes, int n_in,
                              void* d_out, int out_size, void* d_ws, size_t ws_size,
                              hipStream_t stream) {
    const float* x      = (const float*)d_in[0];
    const float* W_ih1  = (const float*)d_in[1];
    const float* W_hh1  = (const float*)d_in[2];
    const float* b_ih1  = (const float*)d_in[3];
    const float* b_hh1  = (const float*)d_in[4];
    const float* W_ih2  = (const float*)d_in[5];
    const float* W_hh2  = (const float*)d_in[6];
    const float* b_ih2  = (const float*)d_in[7];
    const float* b_hh2  = (const float*)d_in[8];
    const float* w_attn = (const float*)d_in[9];
    const float* b_attn = (const float*)d_in[10];
    const float* w1     = (const float*)d_in[11];
    const float* b1     = (const float*)d_in[12];
    const float* w2     = (const float*)d_in[13];
    const float* b2     = (const float*)d_in[14];

    char* ws = (char*)d_ws;
    size_t off = 0;
    auto alloc = [&](size_t bytes) { size_t r = off; off = (off + bytes + 255) & ~(size_t)255; return r; };

    size_t o_bar  = alloc(1024);                      // 128+64 flags + diag flag
    size_t o_wih2 = alloc((size_t)G4_ * H_ * 2);      // 8 MB bf16 (for v-gemm)
    size_t o_xb   = alloc((size_t)B_ * T_ * F_ * 2);  // 32 MB
    size_t o_b1s  = alloc(G4_ * 4);
    size_t o_b2s  = alloc(G4_ * 4);
    size_t o_ct   = alloc(B_ * T_ * 4);
    size_t o_ccb  = alloc(B_ * F_ * 2);
    size_t o_v    = alloc((size_t)B_ * G4_ * 4);      // 1 MB
    size_t o_h1   = alloc(2 * B_ * H_ * 2);
    size_t o_h2   = alloc(2 * B_ * H_ * 2);
    size_t o_outl = alloc(B_ * H_ * 4);
    size_t o_w1t  = alloc(64 * H_ * 2);
    size_t o_msm  = alloc(B_ * H_ * 4);
    size_t o_ssm  = alloc(B_ * H_ * 4);
    size_t o_tap  = alloc(B_ * T_ * 4);
    size_t o_enc  = alloc((size_t)B_ * T_ * H_ * 2);  // 32 MB bf16
    size_t o_saa  = o_xb;                             // alias: xb dead after recurrence
    size_t o_r1   = o_enc;                            // alias: enc dead after p2

    if (ws_size < off) return;  // fail loudly as absmax mismatch, never a fault

    unsigned* bar  = (unsigned*)(ws + o_bar);
    bf16_t* wih2b  = (bf16_t*)(ws + o_wih2);
    bf16_t* xb     = (bf16_t*)(ws + o_xb);
    float*  b1s    = (float*)(ws + o_b1s);
    float*  b2s    = (float*)(ws + o_b2s);
    float*  ctp    = (float*)(ws + o_ct);
    bf16_t* ccb    = (bf16_t*)(ws + o_ccb);
    float*  vbuf   = (float*)(ws + o_v);
    bf16_t* h1     = (bf16_t*)(ws + o_h1);
    bf16_t* h2     = (bf16_t*)(ws + o_h2);
    float*  outl   = (float*)(ws + o_outl);
    bf16_t* w1t    = (bf16_t*)(ws + o_w1t);
    float*  msm    = (float*)(ws + o_msm);
    float*  ssm    = (float*)(ws + o_ssm);
    float*  tap    = (float*)(ws + o_tap);
    bf16_t* encp   = (bf16_t*)(ws + o_enc);
    bf16_t* saa    = (bf16_t*)(ws + o_saa);
    float*  r1     = (float*)(ws + o_r1);

    hipMemsetAsync(ws + o_bar, 0, 1024, stream);

    int n = G4_ * H_;
    cast_kernel<<<(n + 255) / 256, 256, 0, stream>>>(W_ih2, wih2b, n);
    n = B_ * T_ * F_;
    cast_kernel<<<(n + 255) / 256, 256, 0, stream>>>(x, xb, n);
    bias_sum_kernel<<<16, 256, 0, stream>>>(b_ih1, b_hh1, b1s, G4_);
    bias_sum_kernel<<<16, 256, 0, stream>>>(b_ih2, b_hh2, b2s, G4_);
    cov1_kernel<<<B_ * T_ / 4, 256, 0, stream>>>(x, ctp);
    cov2_kernel<<<B_, 256, 0, stream>>>(x, ccb);
    w1t_kernel<<<256, 256, 0, stream>>>(w1, w1t);

    // v = cov_chan * Wih2^T (fp32 out)
    gemm_bt_kernel<<<dim3(G4_ / 64, 1), 256, 0, stream>>>(ccb, wih2b, nullptr, vbuf, B_, G4_, H_);

    lstm_recur_kernel<<<NBLK_, 256, 0, stream>>>(
        xb, ctp, vbuf, b1s, b2s, W_ih1, W_hh1, W_hh2, h1, h2, encp, outl, bar);

    p1_kernel<<<B_, 256, 0, stream>>>(encp, msm, ssm);
    p2_kernel<<<B_ * T_, 256, 0, stream>>>(encp, msm, ssm, outl, w_attn, saa, tap);
    // r1 = saa * w1T^T + b1 (fp32 out)
    gemm_bt_kernel<<<dim3(1, B_ * T_ / 128), 256, 0, stream>>>(saa, w1t, b1, r1, B_ * T_, 64, H_);
    p4_kernel<<<B_ * T_ / 4, 256, 0, stream>>>(r1, w2, b2, tap, b_attn, bar + 224, (float*)d_out);

    (void)in_sizes; (void)n_in; (void)out_size;
}

// Round 4
// 3433.855 us; speedup vs baseline: 1.6362x; 1.1147x over previous
//
#include <hip/hip_runtime.h>

typedef __bf16 bf16_t;
typedef __bf16 bf16x8 __attribute__((ext_vector_type(8)));
typedef float f32x4 __attribute__((ext_vector_type(4)));
typedef int i32x4 __attribute__((ext_vector_type(4)));
typedef unsigned long long u64;

#define B_ 64
#define T_ 256
#define F_ 1024
#define H_ 1024
#define G4_ 4096
#define NBLK_ 192
#define LPAD_ 1032   // row stride (elems): 2064B = 16B-aligned, worst 2-way LDS conflict (free)

#define MFMA16 __builtin_amdgcn_mfma_f32_16x16x32_bf16

__device__ __forceinline__ float sig_fast(float x) { return 1.f / (1.f + __expf(-x)); }
__device__ __forceinline__ float tanh_fast(float x) {
    float e = __expf(2.f * x);
    return 1.f - 2.f / (e + 1.f);
}
__device__ __forceinline__ float waveReduceSum(float v) {
    #pragma unroll
    for (int off = 32; off > 0; off >>= 1) v += __shfl_xor(v, off);
    return v;
}

// ---- agent-coherent (sc0 sc1) helpers: per-instruction coherence, NO cache fences ----
__device__ __forceinline__ void atom_store_u32(unsigned* p, unsigned v) {
    __hip_atomic_store(p, v, __ATOMIC_RELAXED, __HIP_MEMORY_SCOPE_AGENT);
}
// 16B LLC-direct load (bypasses stale L1/L2). Result NOT valid until an
// explicit s_waitcnt vmcnt(N) retires it — callers use WAITV below.
__device__ __forceinline__ i32x4 llc_load16(const bf16_t* p) {
    i32x4 r;
    asm volatile("global_load_dwordx4 %0, %1, off sc0 sc1"
                 : "=v"(r) : "v"(p) : "memory");
    return r;
}
// hand-placed vmem wait + hard scheduling fence (rule: MFMA must not hoist
// above the waitcnt that makes its operand valid)
#define WAITV(N) do { asm volatile("s_waitcnt vmcnt(" #N ")" ::: "memory"); \
                      __builtin_amdgcn_sched_barrier(0); } while (0)

__device__ __forceinline__ unsigned bf16_bits(float f) {
    unsigned short s = __builtin_bit_cast(unsigned short, (bf16_t)f);
    return (unsigned)s;
}

// ---- per-wave flag barrier (publish / wait), fence-free, no __syncthreads ----
// Wave w of any block touches only h rows [16w,16w+16): stamps are per
// (block,wave). Publisher: drain own stores (vmcnt(0)) then write-through
// stamp. Consumer wave w: poll stamps [b*4+w] for all producers b.
__device__ __forceinline__ void wave_publish(unsigned* grp, int gidx, int wave, int lane,
                                             unsigned stamp) {
    asm volatile("s_waitcnt vmcnt(0)" ::: "memory");
    if (lane == 0)
        __hip_atomic_store(grp + (gidx * 4 + wave), stamp, __ATOMIC_RELAXED,
                           __HIP_MEMORY_SCOPE_AGENT);
}

__device__ __forceinline__ void wave_wait(const unsigned* grp, int gn, int wave, int lane,
                                          unsigned stamp, unsigned* flag) {
    const unsigned* p0 = grp + (lane * 4 + wave);
    int spins = 0;
    while (__hip_atomic_load(p0, __ATOMIC_RELAXED, __HIP_MEMORY_SCOPE_AGENT) < stamp) {
        if ((++spins & 2047) == 0) {
            if (__hip_atomic_load(flag, __ATOMIC_RELAXED, __HIP_MEMORY_SCOPE_AGENT)) break;
            if (spins > 4000000) {
                __hip_atomic_fetch_or(flag, 1u, __ATOMIC_RELAXED, __HIP_MEMORY_SCOPE_AGENT);
                break;
            }
        }
    }
    if (gn > 64) {
        const unsigned* p1 = grp + ((lane + 64) * 4 + wave);
        spins = 0;
        while (__hip_atomic_load(p1, __ATOMIC_RELAXED, __HIP_MEMORY_SCOPE_AGENT) < stamp) {
            if ((++spins & 2047) == 0) {
                if (__hip_atomic_load(flag, __ATOMIC_RELAXED, __HIP_MEMORY_SCOPE_AGENT)) break;
                if (spins > 4000000) {
                    __hip_atomic_fetch_or(flag, 1u, __ATOMIC_RELAXED, __HIP_MEMORY_SCOPE_AGENT);
                    break;
                }
            }
        }
    }
}

// ---- pipelined h-phase building blocks ----
__device__ __forceinline__ void loadh8(i32x4* d, const bf16_t* base, int c) {
    #pragma unroll
    for (int j = 0; j < 8; ++j) d[j] = llc_load16(base + (c * 8 + j) * 32);
}
__device__ __forceinline__ void mfmah2(f32x4& a0, f32x4& a1, const i32x4* hf,
                                       const bf16_t* B0, const bf16_t* B1, int c) {
    #pragma unroll
    for (int j = 0; j < 8; ++j) {
        bf16x8 h8 = __builtin_bit_cast(bf16x8, hf[j]);
        a0 = MFMA16(h8, *(const bf16x8*)(B0 + (c * 8 + j) * 32), a0, 0, 0, 0);
        a1 = MFMA16(h8, *(const bf16x8*)(B1 + (c * 8 + j) * 32), a1, 0, 0, 0);
    }
}
__device__ __forceinline__ void mfmah4(f32x4* acc, const i32x4* hf,
                                       const bf16_t* B0, const bf16_t* B1,
                                       const bf16_t* B2, const bf16_t* B3, int c) {
    #pragma unroll
    for (int j = 0; j < 8; ++j) {
        bf16x8 h8 = __builtin_bit_cast(bf16x8, hf[j]);
        acc[0] = MFMA16(h8, *(const bf16x8*)(B0 + (c * 8 + j) * 32), acc[0], 0, 0, 0);
        acc[1] = MFMA16(h8, *(const bf16x8*)(B1 + (c * 8 + j) * 32), acc[1], 0, 0, 0);
        acc[2] = MFMA16(h8, *(const bf16x8*)(B2 + (c * 8 + j) * 32), acc[2], 0, 0, 0);
        acc[3] = MFMA16(h8, *(const bf16x8*)(B3 + (c * 8 + j) * 32), acc[3], 0, 0, 0);
    }
}

// ---------------- small prep kernels ----------------

__global__ void cast_kernel(const float* __restrict__ src, bf16_t* __restrict__ dst, int n) {
    int i = blockIdx.x * 256 + threadIdx.x;
    if (i < n) dst[i] = (bf16_t)src[i];
}

__global__ void bias_sum_kernel(const float* __restrict__ a, const float* __restrict__ b,
                                float* __restrict__ dst, int n) {
    int i = blockIdx.x * 256 + threadIdx.x;
    if (i < n) dst[i] = a[i] + b[i];
}

// w1 [1024,64] -> w1T bf16 [64,1024]
__global__ void w1t_kernel(const float* __restrict__ w1, bf16_t* __restrict__ w1T) {
    int i = blockIdx.x * 256 + threadIdx.x;  // 65536
    int j = i >> 10, u = i & 1023;
    w1T[i] = (bf16_t)w1[u * 64 + j];
}

// cov_temp[b,t] = (b%32==31)?0 : max(0, (sum_f x^2 - (sum_f x)^2/F)/T)
__global__ __launch_bounds__(256) void cov1_kernel(const float* __restrict__ x, float* __restrict__ ct) {
    int row = blockIdx.x * 4 + (threadIdx.x >> 6);  // b*T+t
    int lane = threadIdx.x & 63;
    const float* xr = x + (size_t)row * F_;
    float s1 = 0.f, s2 = 0.f;
    for (int f = lane; f < F_; f += 64) { float v = xr[f]; s1 += v; s2 += v * v; }
    s1 = waveReduceSum(s1);
    s2 = waveReduceSum(s2);
    if (lane == 0) {
        int b = row >> 8;
        float c = (s2 - s1 * s1 * (1.f / F_)) * (1.f / T_);
        ct[row] = ((b & 31) == 31) ? 0.f : fmaxf(c, 0.f);
    }
}

// cov_chan[b,f] (bf16) = (b%32==31)?0 : max(0, (sum_t x^2 - (sum_t x)^2/T)/F)
__global__ __launch_bounds__(256) void cov2_kernel(const float* __restrict__ x,
                                                   bf16_t* __restrict__ ccb) {
    int b = blockIdx.x;
    #pragma unroll
    for (int j = 0; j < 4; ++j) {
        int f = threadIdx.x + j * 256;
        float s1 = 0.f, s2 = 0.f;
        for (int t = 0; t < T_; ++t) {
            float v = x[((size_t)b * T_ + t) * F_ + f];
            s1 += v; s2 += v * v;
        }
        float c = (s2 - s1 * s1 * (1.f / T_)) * (1.f / F_);
        if ((b & 31) == 31) c = 0.f;
        ccb[b * F_ + f] = (bf16_t)fmaxf(c, 0.f);
    }
}

// ---------------- generic MFMA GEMM: C[M,N] = A[M,K] * B[N,K]^T (+bias) ----------------
__global__ __launch_bounds__(256) void gemm_bt_kernel(
    const bf16_t* __restrict__ A, const bf16_t* __restrict__ B,
    const float* __restrict__ bias, float* __restrict__ C,
    int M, int N, int K)
{
    const int wave = threadIdx.x >> 6;
    const int lane = threadIdx.x & 63;
    const int ln15 = lane & 15;
    const int quad = lane >> 4;
    const int n_base = blockIdx.x * 64;
    const int m_wave = blockIdx.y * 128 + wave * 32;

    f32x4 acc[2][4] = {};

    int rowA0 = m_wave + ln15;       if (rowA0 >= M) rowA0 = M - 1;
    int rowA1 = m_wave + 16 + ln15;  if (rowA1 >= M) rowA1 = M - 1;
    const bf16_t* Arow0 = A + (size_t)rowA0 * K + quad * 8;
    const bf16_t* Arow1 = A + (size_t)rowA1 * K + quad * 8;
    const bf16_t* Brow0 = B + (size_t)(n_base + 0 * 16 + ln15) * K + quad * 8;
    const bf16_t* Brow1 = B + (size_t)(n_base + 1 * 16 + ln15) * K + quad * 8;
    const bf16_t* Brow2 = B + (size_t)(n_base + 2 * 16 + ln15) * K + quad * 8;
    const bf16_t* Brow3 = B + (size_t)(n_base + 3 * 16 + ln15) * K + quad * 8;

    for (int k0 = 0; k0 < K; k0 += 32) {
        bf16x8 a0 = *(const bf16x8*)(Arow0 + k0);
        bf16x8 a1 = *(const bf16x8*)(Arow1 + k0);
        bf16x8 b0 = *(const bf16x8*)(Brow0 + k0);
        bf16x8 b1 = *(const bf16x8*)(Brow1 + k0);
        bf16x8 b2 = *(const bf16x8*)(Brow2 + k0);
        bf16x8 b3 = *(const bf16x8*)(Brow3 + k0);
        acc[0][0] = MFMA16(a0, b0, acc[0][0], 0, 0, 0);
        acc[0][1] = MFMA16(a0, b1, acc[0][1], 0, 0, 0);
        acc[0][2] = MFMA16(a0, b2, acc[0][2], 0, 0, 0);
        acc[0][3] = MFMA16(a0, b3, acc[0][3], 0, 0, 0);
        acc[1][0] = MFMA16(a1, b0, acc[1][0], 0, 0, 0);
        acc[1][1] = MFMA16(a1, b1, acc[1][1], 0, 0, 0);
        acc[1][2] = MFMA16(a1, b2, acc[1][2], 0, 0, 0);
        acc[1][3] = MFMA16(a1, b3, acc[1][3], 0, 0, 0);
    }

    #pragma unroll
    for (int s = 0; s < 2; ++s) {
        #pragma unroll
        for (int g = 0; g < 4; ++g) {
            int col = n_base + g * 16 + ln15;
            float bv = bias ? bias[col] : 0.f;
            #pragma unroll
            for (int r = 0; r < 4; ++r) {
                int row = m_wave + s * 16 + quad * 4 + r;
                if (row < M) C[(size_t)row * N + col] = acc[s][g][r] + bv;
            }
        }
    }
}

// ---------------- persistent dual-LSTM recurrence ----------------
// blocks 0..127:  LSTM1, 8 units each; blocks 128..191: LSTM2, 16 units each.
// Per-wave pipelines: wave w owns h rows [16w,16w+16) for read AND write, so
// stamps are per (block,wave) and the loop has NO __syncthreads.
// h exchange: packed-u32 agent atomic stores (write-through to LLC) and
// asm global_load_dwordx4 sc0 sc1 reads with hand-pipelined vmcnt waits.
__global__ __launch_bounds__(256, 1) void lstm_recur_kernel(
    const bf16_t* __restrict__ xb,    // [B,T,F] bf16
    const float*  __restrict__ ct,    // [B,T]
    const float*  __restrict__ v,     // [B,4096] fp32
    const float*  __restrict__ b1s,   // [4096]
    const float*  __restrict__ b2s,   // [4096]
    const float*  __restrict__ wih1,  // [4096,1024] fp32
    const float*  __restrict__ whh1,  // [4096,1024] fp32
    const float*  __restrict__ whh2,  // [4096,1024] fp32
    bf16_t* __restrict__ h1buf,       // [2][B][H] bf16
    bf16_t* __restrict__ h2buf,
    bf16_t* __restrict__ enc,         // [B,T,H] bf16
    float*  __restrict__ outl,        // [B,H] fp32
    unsigned* __restrict__ bar)
{
    __shared__ bf16_t wlds[64 * LPAD_];  // 132096 B

    const int blk  = blockIdx.x;
    const int is2  = (blk >= 128);
    const int wave = threadIdx.x >> 6;
    const int lane = threadIdx.x & 63;
    const int ln15 = lane & 15;
    const int quad = lane >> 4;
    const int bw   = wave * 16;

    unsigned* grp  = is2 ? (bar + 512) : bar;   // per-(block,wave) stamp words
    const int gidx = is2 ? (blk - 128) : blk;
    const int gn   = is2 ? 64 : 128;
    unsigned* flag = bar + 992;                 // timeout diagnostic

    int u0;
    if (!is2) {
        u0 = blk * 8;
        for (int i = threadIdx.x; i < 2 * 32 * 128; i += 256) {
            int mat = i >> 12;
            int rem = i & 4095;
            int n = rem >> 7;
            int kc = (rem & 127) * 8;
            int gate = n >> 3, unit = n & 7;
            const float* src = (mat ? whh1 : wih1) + (size_t)(gate * 1024 + u0 + unit) * H_ + kc;
            float4 f0 = *(const float4*)(src);
            float4 f1 = *(const float4*)(src + 4);
            bf16x8 w;
            w[0] = (bf16_t)f0.x; w[1] = (bf16_t)f0.y; w[2] = (bf16_t)f0.z; w[3] = (bf16_t)f0.w;
            w[4] = (bf16_t)f1.x; w[5] = (bf16_t)f1.y; w[6] = (bf16_t)f1.z; w[7] = (bf16_t)f1.w;
            *(bf16x8*)&wlds[(mat * 32 + n) * LPAD_ + kc] = w;
        }
        // zero-init h1 buf0 (write-through so it's visible without fences)
        for (int i = threadIdx.x; i < 64 * 4; i += 256)
            atom_store_u32((unsigned*)h1buf + (size_t)(i >> 2) * (H_ / 2) + (u0 >> 1) + (i & 3), 0u);
    } else {
        u0 = (blk - 128) * 16;
        for (int i = threadIdx.x; i < 64 * 128; i += 256) {
            int n = i >> 7;
            int kc = (i & 127) * 8;
            int gate = n >> 4, unit = n & 15;
            const float* src = whh2 + (size_t)(gate * 1024 + u0 + unit) * H_ + kc;
            float4 f0 = *(const float4*)(src);
            float4 f1 = *(const float4*)(src + 4);
            bf16x8 w;
            w[0] = (bf16_t)f0.x; w[1] = (bf16_t)f0.y; w[2] = (bf16_t)f0.z; w[3] = (bf16_t)f0.w;
            w[4] = (bf16_t)f1.x; w[5] = (bf16_t)f1.y; w[6] = (bf16_t)f1.z; w[7] = (bf16_t)f1.w;
            *(bf16x8*)&wlds[n * LPAD_ + kc] = w;
        }
        for (int i = threadIdx.x; i < 64 * 8; i += 256)
            atom_store_u32((unsigned*)h2buf + (size_t)(i >> 3) * (H_ / 2) + (u0 >> 1) + (i & 7), 0u);
    }

    // per-thread constants
    float bias0 = 0.f, bias1 = 0.f;
    float vreg[4][4];
    float b2reg[4];
    if (!is2) {
        int col0 = (ln15 < 8) ? (u0 + ln15) : (1024 + u0 + ln15 - 8);
        int col1 = (ln15 < 8) ? (2048 + u0 + ln15) : (3072 + u0 + ln15 - 8);
        bias0 = b1s[col0];
        bias1 = b1s[col1];
    } else {
        #pragma unroll
        for (int g = 0; g < 4; ++g) {
            int colg = g * 1024 + u0 + ln15;
            b2reg[g] = b2s[colg];
            #pragma unroll
            for (int r = 0; r < 4; ++r)
                vreg[g][r] = v[(size_t)(bw + quad * 4 + r) * G4_ + colg];
        }
    }

    // staging + zero-init visible: block barrier drains every wave's stores,
    // then each wave publishes stamp 1.
    __syncthreads();
    if (lane == 0)
        __hip_atomic_store(grp + (gidx * 4 + wave), 1u, __ATOMIC_RELAXED,
                           __HIP_MEMORY_SCOPE_AGENT);

    const bf16_t* hread  = is2 ? h2buf : h1buf;
    bf16_t*       hwrite = (is2 ? h2buf : h1buf) + B_ * H_;

    float c_st[4] = {0.f, 0.f, 0.f, 0.f};

    if (!is2) {
        unsigned stamp = 2;
        const bf16_t* xB0 = &wlds[(0 + ln15) * LPAD_ + quad * 8];
        const bf16_t* xB1 = &wlds[(16 + ln15) * LPAD_ + quad * 8];
        const bf16_t* hB0 = &wlds[(32 + ln15) * LPAD_ + quad * 8];
        const bf16_t* hB1 = &wlds[(48 + ln15) * LPAD_ + quad * 8];
        for (int t = 0; t < T_; ++t) {
            // ---- x-phase: L2 loads, 2-buffer rotation; overlaps publish->discover ----
            const bf16_t* xA = xb + ((size_t)(bw + ln15) * T_ + t) * F_ + quad * 8;
            f32x4 acc0 = {}, acc1 = {};
            {
                bf16x8 xa[8], xc[8];
                #pragma unroll
                for (int j = 0; j < 8; ++j) xa[j] = *(const bf16x8*)(xA + j * 32);
                __builtin_amdgcn_sched_barrier(0);
                #pragma unroll
                for (int j = 0; j < 8; ++j) xc[j] = *(const bf16x8*)(xA + (8 + j) * 32);
                __builtin_amdgcn_sched_barrier(0);
                #pragma unroll
                for (int j = 0; j < 8; ++j) {
                    acc0 = MFMA16(xa[j], *(const bf16x8*)(xB0 + j * 32), acc0, 0, 0, 0);
                    acc1 = MFMA16(xa[j], *(const bf16x8*)(xB1 + j * 32), acc1, 0, 0, 0);
                }
                __builtin_amdgcn_sched_barrier(0);
                #pragma unroll
                for (int j = 0; j < 8; ++j) xa[j] = *(const bf16x8*)(xA + (16 + j) * 32);
                __builtin_amdgcn_sched_barrier(0);
                #pragma unroll
                for (int j = 0; j < 8; ++j) {
                    acc0 = MFMA16(xc[j], *(const bf16x8*)(xB0 + (8 + j) * 32), acc0, 0, 0, 0);
                    acc1 = MFMA16(xc[j], *(const bf16x8*)(xB1 + (8 + j) * 32), acc1, 0, 0, 0);
                }
                __builtin_amdgcn_sched_barrier(0);
                #pragma unroll
                for (int j = 0; j < 8; ++j) xc[j] = *(const bf16x8*)(xA + (24 + j) * 32);
                __builtin_amdgcn_sched_barrier(0);
                #pragma unroll
                for (int j = 0; j < 8; ++j) {
                    acc0 = MFMA16(xa[j], *(const bf16x8*)(xB0 + (16 + j) * 32), acc0, 0, 0, 0);
                    acc1 = MFMA16(xa[j], *(const bf16x8*)(xB1 + (16 + j) * 32), acc1, 0, 0, 0);
                }
                #pragma unroll
                for (int j = 0; j < 8; ++j) {
                    acc0 = MFMA16(xc[j], *(const bf16x8*)(xB0 + (24 + j) * 32), acc0, 0, 0, 0);
                    acc1 = MFMA16(xc[j], *(const bf16x8*)(xB1 + (24 + j) * 32), acc1, 0, 0, 0);
                }
            }
            // ---- h[t-1] ready? (per-wave stamps) ----
            wave_wait(grp, gn, wave, lane, stamp - 1, flag);
            // ---- pipelined LLC h loads: 4 chunks x 8 frags, 2 in flight ----
            const bf16_t* hA = hread + (size_t)(bw + ln15) * H_ + quad * 8;
            {
                i32x4 ha[8], hc[8];
                loadh8(ha, hA, 0);
                loadh8(hc, hA, 1);
                WAITV(8);
                mfmah2(acc0, acc1, ha, hB0, hB1, 0);
                loadh8(ha, hA, 2);
                WAITV(8);
                mfmah2(acc0, acc1, hc, hB0, hB1, 1);
                loadh8(hc, hA, 3);
                WAITV(8);
                mfmah2(acc0, acc1, ha, hB0, hB1, 2);
                WAITV(0);
                mfmah2(acc0, acc1, hc, hB0, hB1, 3);
            }
            #pragma unroll
            for (int r = 0; r < 4; ++r) {
                int b = bw + quad * 4 + r;
                float p0 = acc0[r] + bias0;          // i (ln15<8) or f (ln15>=8)
                float p1 = acc1[r] + bias1;          // g or o
                float q0 = __shfl_xor(p0, 8);
                float q1 = __shfl_xor(p1, 8);
                float ig = (ln15 < 8) ? p0 : q0;
                float fg = (ln15 < 8) ? q0 : p0;
                float gg = (ln15 < 8) ? p1 : q1;
                float og = (ln15 < 8) ? q1 : p1;
                ig = sig_fast(ig); fg = sig_fast(fg);
                gg = tanh_fast(gg); og = sig_fast(og);
                float c = fg * c_st[r] + ig * gg;
                c_st[r] = c;
                float h = og * tanh_fast(c);
                unsigned hv = bf16_bits(h);
                unsigned pv = __shfl_xor(hv, 1);     // partner unit's h (ln15 xor 1)
                if ((ln15 & 1) == 0 && ln15 < 8)
                    atom_store_u32((unsigned*)hwrite + (size_t)b * (H_ / 2) + ((u0 + ln15) >> 1),
                                   hv | (pv << 16));
                if (ln15 < 8 && t == T_ - 1) outl[(size_t)b * H_ + u0 + ln15] = h;
            }
            wave_publish(grp, gidx, wave, lane, stamp);
            stamp++;
            bf16_t* tmp = (bf16_t*)hread; hread = hwrite; hwrite = tmp;
        }
    } else {
        unsigned stamp = 2;
        const bf16_t* B0 = &wlds[(0 * 16 + ln15) * LPAD_ + quad * 8];
        const bf16_t* B1 = &wlds[(1 * 16 + ln15) * LPAD_ + quad * 8];
        const bf16_t* B2 = &wlds[(2 * 16 + ln15) * LPAD_ + quad * 8];
        const bf16_t* B3 = &wlds[(3 * 16 + ln15) * LPAD_ + quad * 8];
        for (int t = 0; t < T_; ++t) {
            // prefetch this step's ct scalars before the wait (cached loads)
            float cts_r[4];
            #pragma unroll
            for (int r = 0; r < 4; ++r) cts_r[r] = ct[(bw + quad * 4 + r) * T_ + t];
            wave_wait(grp, gn, wave, lane, stamp - 1, flag);
            const bf16_t* hA = hread + (size_t)(bw + ln15) * H_ + quad * 8;
            f32x4 acc[4] = {};
            {
                i32x4 ha[8], hc[8];
                loadh8(ha, hA, 0);
                loadh8(hc, hA, 1);
                WAITV(8);
                mfmah4(acc, ha, B0, B1, B2, B3, 0);
                loadh8(ha, hA, 2);
                WAITV(8);
                mfmah4(acc, hc, B0, B1, B2, B3, 1);
                loadh8(hc, hA, 3);
                WAITV(8);
                mfmah4(acc, ha, B0, B1, B2, B3, 2);
                WAITV(0);
                mfmah4(acc, hc, B0, B1, B2, B3, 3);
            }
            #pragma unroll
            for (int r = 0; r < 4; ++r) {
                int b = bw + quad * 4 + r;
                float cts = cts_r[r];
                float ig = sig_fast(acc[0][r] + cts * vreg[0][r] + b2reg[0]);
                float fg = sig_fast(acc[1][r] + cts * vreg[1][r] + b2reg[1]);
                float gg = tanh_fast(acc[2][r] + cts * vreg[2][r] + b2reg[2]);
                float og = sig_fast(acc[3][r] + cts * vreg[3][r] + b2reg[3]);
                float c = fg * c_st[r] + ig * gg;
                c_st[r] = c;
                float h = og * tanh_fast(c);
                unsigned hv = bf16_bits(h);
                unsigned pv = __shfl_xor(hv, 1);
                if ((ln15 & 1) == 0) {
                    unsigned word = hv | (pv << 16);
                    atom_store_u32((unsigned*)hwrite + (size_t)b * (H_ / 2) + ((u0 + ln15) >> 1), word);
                    // enc is consumed only after kernel end -> normal (dirty-L2) store is fine
                    *((unsigned*)enc + ((size_t)b * T_ + t) * (H_ / 2) + ((u0 + ln15) >> 1)) = word;
                }
            }
            wave_publish(grp, gidx, wave, lane, stamp);
            stamp++;
            bf16_t* tmp = (bf16_t*)hread; hread = hwrite; hwrite = tmp;
        }
    }
}

// ---------------- attention epilogue ----------------

__global__ __launch_bounds__(256) void p1_kernel(const bf16_t* __restrict__ enc,
                                                 float* __restrict__ Msm, float* __restrict__ Ssm) {
    int b = blockIdx.x;
    #pragma unroll
    for (int j = 0; j < 4; ++j) {
        int u = threadIdx.x + j * 256;
        const bf16_t* e = enc + (size_t)b * T_ * H_ + u;
        float m = -1e30f;
        for (int t = 0; t < T_; ++t) m = fmaxf(m, (float)e[(size_t)t * H_]);
        float s = 0.f;
        for (int t = 0; t < T_; ++t) s += __expf((float)e[(size_t)t * H_] - m);
        Msm[b * H_ + u] = m;
        Ssm[b * H_ + u] = s;
    }
}

__global__ __launch_bounds__(256) void p2_kernel(
    const bf16_t* __restrict__ enc, const float* __restrict__ Msm, const float* __restrict__ Ssm,
    const float* __restrict__ outl, const float* __restrict__ w_attn,
    bf16_t* __restrict__ saa, float* __restrict__ tapre) {
    int row = blockIdx.x;   // b*T+t
    int b = row >> 8;
    const bf16_t* erow = enc + (size_t)row * H_;
    float tsum = 0.f;
    for (int u = threadIdx.x; u < H_; u += 256) {
        float e = (float)erow[u];
        float sp = __expf(e - Msm[b * H_ + u]) / Ssm[b * H_ + u];
        saa[(size_t)row * H_ + u] = (bf16_t)(outl[b * H_ + u] * (sp + 1.f));
        tsum += tanh_fast(e) * w_attn[u];
    }
    tsum = waveReduceSum(tsum);
    __shared__ float red[4];
    if ((threadIdx.x & 63) == 0) red[threadIdx.x >> 6] = tsum;
    __syncthreads();
    if (threadIdx.x == 0) tapre[row] = red[0] + red[1] + red[2] + red[3];
}

// final: det = sigmoid(relu(r1)@w2 + b2); out = det*(1+sigmoid(tapre+b_attn))  [fp32 out]
__global__ __launch_bounds__(256) void p4_kernel(
    const float* __restrict__ r1, const float* __restrict__ w2, const float* __restrict__ b2,
    const float* __restrict__ tapre, const float* __restrict__ b_attn,
    const unsigned* __restrict__ flag, float* __restrict__ out) {
    int row = blockIdx.x * 4 + (threadIdx.x >> 6);
    int lane = threadIdx.x & 63;
    float vsum = fmaxf(r1[(size_t)row * 64 + lane], 0.f) * w2[lane];
    vsum = waveReduceSum(vsum);
    if (lane == 0) {
        float det = sig_fast(vsum + b2[0]);
        float ta = sig_fast(tapre[row] + b_attn[0]);
        out[row] = det * (1.f + ta) + 1000.f * (float)(*flag);
    }
}

// ---------------- launcher ----------------

extern "C" void kernel_launch(void* const* d_in, const int* in_sizes, int n_in,
                              void* d_out, int out_size, void* d_ws, size_t ws_size,
                              hipStream_t stream) {
    const float* x      = (const float*)d_in[0];
    const float* W_ih1  = (const float*)d_in[1];
    const float* W_hh1  = (const float*)d_in[2];
    const float* b_ih1  = (const float*)d_in[3];
    const float* b_hh1  = (const float*)d_in[4];
    const float* W_ih2  = (const float*)d_in[5];
    const float* W_hh2  = (const float*)d_in[6];
    const float* b_ih2  = (const float*)d_in[7];
    const float* b_hh2  = (const float*)d_in[8];
    const float* w_attn = (const float*)d_in[9];
    const float* b_attn = (const float*)d_in[10];
    const float* w1     = (const float*)d_in[11];
    const float* b1     = (const float*)d_in[12];
    const float* w2     = (const float*)d_in[13];
    const float* b2     = (const float*)d_in[14];

    char* ws = (char*)d_ws;
    size_t off = 0;
    auto alloc = [&](size_t bytes) { size_t r = off; off = (off + bytes + 255) & ~(size_t)255; return r; };

    size_t o_bar  = alloc(4096);                      // per-(block,wave) stamps + diag flag
    size_t o_wih2 = alloc((size_t)G4_ * H_ * 2);      // 8 MB bf16 (for v-gemm)
    size_t o_xb   = alloc((size_t)B_ * T_ * F_ * 2);  // 32 MB
    size_t o_b1s  = alloc(G4_ * 4);
    size_t o_b2s  = alloc(G4_ * 4);
    size_t o_ct   = alloc(B_ * T_ * 4);
    size_t o_ccb  = alloc(B_ * F_ * 2);
    size_t o_v    = alloc((size_t)B_ * G4_ * 4);      // 1 MB
    size_t o_h1   = alloc(2 * B_ * H_ * 2);
    size_t o_h2   = alloc(2 * B_ * H_ * 2);
    size_t o_outl = alloc(B_ * H_ * 4);
    size_t o_w1t  = alloc(64 * H_ * 2);
    size_t o_msm  = alloc(B_ * H_ * 4);
    size_t o_ssm  = alloc(B_ * H_ * 4);
    size_t o_tap  = alloc(B_ * T_ * 4);
    size_t o_enc  = alloc((size_t)B_ * T_ * H_ * 2);  // 32 MB bf16
    size_t o_saa  = o_xb;                             // alias: xb dead after recurrence
    size_t o_r1   = o_enc;                            // alias: enc dead after p2

    if (ws_size < off) return;  // fail loudly as absmax mismatch, never a fault

    unsigned* bar  = (unsigned*)(ws + o_bar);
    bf16_t* wih2b  = (bf16_t*)(ws + o_wih2);
    bf16_t* xb     = (bf16_t*)(ws + o_xb);
    float*  b1s    = (float*)(ws + o_b1s);
    float*  b2s    = (float*)(ws + o_b2s);
    float*  ctp    = (float*)(ws + o_ct);
    bf16_t* ccb    = (bf16_t*)(ws + o_ccb);
    float*  vbuf   = (float*)(ws + o_v);
    bf16_t* h1     = (bf16_t*)(ws + o_h1);
    bf16_t* h2     = (bf16_t*)(ws + o_h2);
    float*  outl   = (float*)(ws + o_outl);
    bf16_t* w1t    = (bf16_t*)(ws + o_w1t);
    float*  msm    = (float*)(ws + o_msm);
    float*  ssm    = (float*)(ws + o_ssm);
    float*  tap    = (float*)(ws + o_tap);
    bf16_t* encp   = (bf16_t*)(ws + o_enc);
    bf16_t* saa    = (bf16_t*)(ws + o_saa);
    float*  r1     = (float*)(ws + o_r1);

    hipMemsetAsync(ws + o_bar, 0, 4096, stream);

    int n = G4_ * H_;
    cast_kernel<<<(n + 255) / 256, 256, 0, stream>>>(W_ih2, wih2b, n);
    n = B_ * T_ * F_;
    cast_kernel<<<(n + 255) / 256, 256, 0, stream>>>(x, xb, n);
    bias_sum_kernel<<<16, 256, 0, stream>>>(b_ih1, b_hh1, b1s, G4_);
    bias_sum_kernel<<<16, 256, 0, stream>>>(b_ih2, b_hh2, b2s, G4_);
    cov1_kernel<<<B_ * T_ / 4, 256, 0, stream>>>(x, ctp);
    cov2_kernel<<<B_, 256, 0, stream>>>(x, ccb);
    w1t_kernel<<<256, 256, 0, stream>>>(w1, w1t);

    // v = cov_chan * Wih2^T (fp32 out)
    gemm_bt_kernel<<<dim3(G4_ / 64, 1), 256, 0, stream>>>(ccb, wih2b, nullptr, vbuf, B_, G4_, H_);

    lstm_recur_kernel<<<NBLK_, 256, 0, stream>>>(
        xb, ctp, vbuf, b1s, b2s, W_ih1, W_hh1, W_hh2, h1, h2, encp, outl, bar);

    p1_kernel<<<B_, 256, 0, stream>>>(encp, msm, ssm);
    p2_kernel<<<B_ * T_, 256, 0, stream>>>(encp, msm, ssm, outl, w_attn, saa, tap);
    // r1 = saa * w1T^T + b1 (fp32 out)
    gemm_bt_kernel<<<dim3(1, B_ * T_ / 128), 256, 0, stream>>>(saa, w1t, b1, r1, B_ * T_, 64, H_);
    p4_kernel<<<B_ * T_ / 4, 256, 0, stream>>>(r1, w2, b2, tap, b_attn, bar + 992, (float*)d_out);

    (void)in_sizes; (void)n_in; (void)out_size;
}

// Round 6
// 3166.539 us; speedup vs baseline: 1.7743x; 1.0844x over previous
//
#include <hip/hip_runtime.h>

typedef __bf16 bf16_t;
typedef __bf16 bf16x8 __attribute__((ext_vector_type(8)));
typedef float f32x4 __attribute__((ext_vector_type(4)));
typedef int i32x4 __attribute__((ext_vector_type(4)));
typedef unsigned long long u64;

#define B_ 64
#define T_ 256
#define F_ 1024
#define H_ 1024
#define G4_ 4096
#define NBLK_ 192
#define LPAD_ 1032   // row stride (elems): 2064B = 16B-aligned, worst 2-way LDS conflict (free)

#define MFMA16 __builtin_amdgcn_mfma_f32_16x16x32_bf16

__device__ __forceinline__ float sig_fast(float x) { return 1.f / (1.f + __expf(-x)); }
__device__ __forceinline__ float tanh_fast(float x) {
    float e = __expf(2.f * x);
    return 1.f - 2.f / (e + 1.f);
}
__device__ __forceinline__ float waveReduceSum(float v) {
    #pragma unroll
    for (int off = 32; off > 0; off >>= 1) v += __shfl_xor(v, off);
    return v;
}

// ---- agent-coherent (sc0 sc1) helpers: per-instruction coherence, NO cache fences ----
__device__ __forceinline__ void atom_store_u32(unsigned* p, unsigned v) {
    __hip_atomic_store(p, v, __ATOMIC_RELAXED, __HIP_MEMORY_SCOPE_AGENT);
}
// 16B LLC-direct load (bypasses stale L1/L2). Result NOT valid until an
// explicit s_waitcnt vmcnt(N) retires it — callers use WAITV below.
__device__ __forceinline__ i32x4 llc_load16(const bf16_t* p) {
    i32x4 r;
    asm volatile("global_load_dwordx4 %0, %1, off sc0 sc1"
                 : "=&v"(r) : "v"(p) : "memory");
    return r;
}
// 16B normally-cached load (L1/L2 path) with the same manual-wait contract.
__device__ __forceinline__ i32x4 l2_load16(const bf16_t* p) {
    i32x4 r;
    asm volatile("global_load_dwordx4 %0, %1, off"
                 : "=&v"(r) : "v"(p) : "memory");
    return r;
}
// hand-placed vmem wait + hard scheduling fence (rule: MFMA must not hoist
// above the waitcnt that makes its operand valid)
#define WAITV(N) do { asm volatile("s_waitcnt vmcnt(" #N ")" ::: "memory"); \
                      __builtin_amdgcn_sched_barrier(0); } while (0)

__device__ __forceinline__ unsigned bf16_bits(float f) {
    unsigned short s = __builtin_bit_cast(unsigned short, (bf16_t)f);
    return (unsigned)s;
}

// ---- heater: 48 independent v_fmac, issued while the poll load is in flight.
// Keeps VALU busy per waiting wave (SCLK governor sees a busy chip) without
// adding discovery latency (~96 cy hides under the ~800 cy LLC flag load).
#define H4_ "v_fmac_f32 %0, %4, %5\n\tv_fmac_f32 %1, %4, %5\n\tv_fmac_f32 %2, %4, %5\n\tv_fmac_f32 %3, %4, %5\n\t"
#define H16_ H4_ H4_ H4_ H4_
#define H48_ H16_ H16_ H16_
#define HEAT() asm volatile(H48_ : "+v"(hh0), "+v"(hh1), "+v"(hh2), "+v"(hh3) \
                            : "v"(hm), "v"(hb))

// ---- per-wave flag barrier (publish / wait), fence-free, no __syncthreads ----
// Wave w of any block touches only h rows [16w,16w+16): stamps are per
// (block,wave). Publisher: drain own stores (vmcnt(0)) then write-through
// stamp. Consumer wave w: poll stamps [b*4+w] for all producers b.
__device__ __forceinline__ void wave_publish(unsigned* grp, int gidx, int wave, int lane,
                                             unsigned stamp) {
    asm volatile("s_waitcnt vmcnt(0)" ::: "memory");
    if (lane == 0)
        __hip_atomic_store(grp + (gidx * 4 + wave), stamp, __ATOMIC_RELAXED,
                           __HIP_MEMORY_SCOPE_AGENT);
}

// Polls one (gn<=64) or two (gn=128) producer flags per lane concurrently.
// The waitcnt asm is data-tied to v0/v1 so the compare cannot hoist above it.
// Hot busy-poll for the first 4096 spins (common case: partner arrives in
// 1-3 polls); then s_sleep-paced (bounded power if something is wrong).
// Timeout latches the diagnostic flag -> all later waits exit in <=32 spins.
__device__ __forceinline__ void wave_wait(const unsigned* grp, int gn, int wave, int lane,
                                          unsigned stamp, unsigned* flag) {
    const unsigned* p0 = grp + (lane * 4 + wave);
    const unsigned* p1 = grp + ((lane + 64) * 4 + wave);
    const bool two = (gn > 64);
    float hh0 = 1.f + lane, hh1 = 2.f, hh2 = 3.f, hh3 = 4.f;
    const float hm = 1.0001f, hb = 0.5f;
    int spins = 0;
    for (;;) {
        unsigned v0, v1 = 0xffffffffu;
        asm volatile("global_load_dword %0, %1, off sc0 sc1"
                     : "=&v"(v0) : "v"(p0) : "memory");
        if (two)
            asm volatile("global_load_dword %0, %1, off sc0 sc1"
                         : "=&v"(v1) : "v"(p1) : "memory");
        HEAT();
        asm volatile("s_waitcnt vmcnt(0)" : "+v"(v0), "+v"(v1) :: "memory");
        if (v0 >= stamp && v1 >= stamp) break;
        ++spins;
        if (spins > 4096) __builtin_amdgcn_s_sleep(1);  // degrade gracefully
        if ((spins & 31) == 0) {
            if (__hip_atomic_load(flag, __ATOMIC_RELAXED, __HIP_MEMORY_SCOPE_AGENT)) break;
            if (spins > 2000000) {  // ~0.7 s paced: latch diagnostic, never hang
                __hip_atomic_fetch_or(flag, 1u, __ATOMIC_RELAXED, __HIP_MEMORY_SCOPE_AGENT);
                break;
            }
        }
    }
}

// ---- pipelined GEMM-phase building blocks ----
__device__ __forceinline__ void loadh8(i32x4* d, const bf16_t* base, int c) {
    #pragma unroll
    for (int j = 0; j < 8; ++j) d[j] = llc_load16(base + (c * 8 + j) * 32);
}
__device__ __forceinline__ void loadl8(i32x4* d, const bf16_t* base, int c) {
    #pragma unroll
    for (int j = 0; j < 8; ++j) d[j] = l2_load16(base + (c * 8 + j) * 32);
}
__device__ __forceinline__ void mfmah2(f32x4& a0, f32x4& a1, const i32x4* hf,
                                       const bf16_t* B0, const bf16_t* B1, int c) {
    #pragma unroll
    for (int j = 0; j < 8; ++j) {
        bf16x8 h8 = __builtin_bit_cast(bf16x8, hf[j]);
        a0 = MFMA16(h8, *(const bf16x8*)(B0 + (c * 8 + j) * 32), a0, 0, 0, 0);
        a1 = MFMA16(h8, *(const bf16x8*)(B1 + (c * 8 + j) * 32), a1, 0, 0, 0);
    }
}
__device__ __forceinline__ void mfmah4(f32x4* acc, const i32x4* hf,
                                       const bf16_t* B0, const bf16_t* B1,
                                       const bf16_t* B2, const bf16_t* B3, int c) {
    #pragma unroll
    for (int j = 0; j < 8; ++j) {
        bf16x8 h8 = __builtin_bit_cast(bf16x8, hf[j]);
        acc[0] = MFMA16(h8, *(const bf16x8*)(B0 + (c * 8 + j) * 32), acc[0], 0, 0, 0);
        acc[1] = MFMA16(h8, *(const bf16x8*)(B1 + (c * 8 + j) * 32), acc[1], 0, 0, 0);
        acc[2] = MFMA16(h8, *(const bf16x8*)(B2 + (c * 8 + j) * 32), acc[2], 0, 0, 0);
        acc[3] = MFMA16(h8, *(const bf16x8*)(B3 + (c * 8 + j) * 32), acc[3], 0, 0, 0);
    }
}

// ---------------- small prep kernels ----------------

__global__ void cast_kernel(const float* __restrict__ src, bf16_t* __restrict__ dst, int n) {
    int i = blockIdx.x * 256 + threadIdx.x;
    if (i < n) dst[i] = (bf16_t)src[i];
}

__global__ void bias_sum_kernel(const float* __restrict__ a, const float* __restrict__ b,
                                float* __restrict__ dst, int n) {
    int i = blockIdx.x * 256 + threadIdx.x;
    if (i < n) dst[i] = a[i] + b[i];
}

// w1 [1024,64] -> w1T bf16 [64,1024]
__global__ void w1t_kernel(const float* __restrict__ w1, bf16_t* __restrict__ w1T) {
    int i = blockIdx.x * 256 + threadIdx.x;  // 65536
    int j = i >> 10, u = i & 1023;
    w1T[i] = (bf16_t)w1[u * 64 + j];
}

// cov_temp[b,t] = (b%32==31)?0 : max(0, (sum_f x^2 - (sum_f x)^2/F)/T)
__global__ __launch_bounds__(256) void cov1_kernel(const float* __restrict__ x, float* __restrict__ ct) {
    int row = blockIdx.x * 4 + (threadIdx.x >> 6);  // b*T+t
    int lane = threadIdx.x & 63;
    const float* xr = x + (size_t)row * F_;
    float s1 = 0.f, s2 = 0.f;
    for (int f = lane; f < F_; f += 64) { float v = xr[f]; s1 += v; s2 += v * v; }
    s1 = waveReduceSum(s1);
    s2 = waveReduceSum(s2);
    if (lane == 0) {
        int b = row >> 8;
        float c = (s2 - s1 * s1 * (1.f / F_)) * (1.f / T_);
        ct[row] = ((b & 31) == 31) ? 0.f : fmaxf(c, 0.f);
    }
}

// cov_chan[b,f] (bf16) = (b%32==31)?0 : max(0, (sum_t x^2 - (sum_t x)^2/T)/F)
__global__ __launch_bounds__(256) void cov2_kernel(const float* __restrict__ x,
                                                   bf16_t* __restrict__ ccb) {
    int b = blockIdx.x;
    #pragma unroll
    for (int j = 0; j < 4; ++j) {
        int f = threadIdx.x + j * 256;
        float s1 = 0.f, s2 = 0.f;
        for (int t = 0; t < T_; ++t) {
            float v = x[((size_t)b * T_ + t) * F_ + f];
            s1 += v; s2 += v * v;
        }
        float c = (s2 - s1 * s1 * (1.f / T_)) * (1.f / F_);
        if ((b & 31) == 31) c = 0.f;
        ccb[b * F_ + f] = (bf16_t)fmaxf(c, 0.f);
    }
}

// ---------------- generic MFMA GEMM: C[M,N] = A[M,K] * B[N,K]^T (+bias) ----------------
__global__ __launch_bounds__(256) void gemm_bt_kernel(
    const bf16_t* __restrict__ A, const bf16_t* __restrict__ B,
    const float* __restrict__ bias, float* __restrict__ C,
    int M, int N, int K)
{
    const int wave = threadIdx.x >> 6;
    const int lane = threadIdx.x & 63;
    const int ln15 = lane & 15;
    const int quad = lane >> 4;
    const int n_base = blockIdx.x * 64;
    const int m_wave = blockIdx.y * 128 + wave * 32;

    f32x4 acc[2][4] = {};

    int rowA0 = m_wave + ln15;       if (rowA0 >= M) rowA0 = M - 1;
    int rowA1 = m_wave + 16 + ln15;  if (rowA1 >= M) rowA1 = M - 1;
    const bf16_t* Arow0 = A + (size_t)rowA0 * K + quad * 8;
    const bf16_t* Arow1 = A + (size_t)rowA1 * K + quad * 8;
    const bf16_t* Brow0 = B + (size_t)(n_base + 0 * 16 + ln15) * K + quad * 8;
    const bf16_t* Brow1 = B + (size_t)(n_base + 1 * 16 + ln15) * K + quad * 8;
    const bf16_t* Brow2 = B + (size_t)(n_base + 2 * 16 + ln15) * K + quad * 8;
    const bf16_t* Brow3 = B + (size_t)(n_base + 3 * 16 + ln15) * K + quad * 8;

    for (int k0 = 0; k0 < K; k0 += 32) {
        bf16x8 a0 = *(const bf16x8*)(Arow0 + k0);
        bf16x8 a1 = *(const bf16x8*)(Arow1 + k0);
        bf16x8 b0 = *(const bf16x8*)(Brow0 + k0);
        bf16x8 b1 = *(const bf16x8*)(Brow1 + k0);
        bf16x8 b2 = *(const bf16x8*)(Brow2 + k0);
        bf16x8 b3 = *(const bf16x8*)(Brow3 + k0);
        acc[0][0] = MFMA16(a0, b0, acc[0][0], 0, 0, 0);
        acc[0][1] = MFMA16(a0, b1, acc[0][1], 0, 0, 0);
        acc[0][2] = MFMA16(a0, b2, acc[0][2], 0, 0, 0);
        acc[0][3] = MFMA16(a0, b3, acc[0][3], 0, 0, 0);
        acc[1][0] = MFMA16(a1, b0, acc[1][0], 0, 0, 0);
        acc[1][1] = MFMA16(a1, b1, acc[1][1], 0, 0, 0);
        acc[1][2] = MFMA16(a1, b2, acc[1][2], 0, 0, 0);
        acc[1][3] = MFMA16(a1, b3, acc[1][3], 0, 0, 0);
    }

    #pragma unroll
    for (int s = 0; s < 2; ++s) {
        #pragma unroll
        for (int g = 0; g < 4; ++g) {
            int col = n_base + g * 16 + ln15;
            float bv = bias ? bias[col] : 0.f;
            #pragma unroll
            for (int r = 0; r < 4; ++r) {
                int row = m_wave + s * 16 + quad * 4 + r;
                if (row < M) C[(size_t)row * N + col] = acc[s][g][r] + bv;
            }
        }
    }
}

// ---------------- persistent dual-LSTM recurrence ----------------
// blocks 0..127:  LSTM1, 8 units each; blocks 128..191: LSTM2, 16 units each.
// Per-wave pipelines: wave w owns h rows [16w,16w+16) for read AND write, so
// stamps are per (block,wave) and the loop has NO __syncthreads.
// h exchange: packed-u32 agent atomic stores (write-through to LLC) and
// asm global_load_dwordx4 sc0 sc1 reads with hand-pipelined vmcnt waits.
// Poll loops run a VALU heater under the flag-load latency (clock boost).
__global__ __launch_bounds__(256, 1) void lstm_recur_kernel(
    const bf16_t* __restrict__ xb,    // [B,T,F] bf16
    const float*  __restrict__ ct,    // [B,T]
    const float*  __restrict__ v,     // [B,4096] fp32
    const float*  __restrict__ b1s,   // [4096]
    const float*  __restrict__ b2s,   // [4096]
    const float*  __restrict__ wih1,  // [4096,1024] fp32
    const float*  __restrict__ whh1,  // [4096,1024] fp32
    const float*  __restrict__ whh2,  // [4096,1024] fp32
    bf16_t* __restrict__ h1buf,       // [2][B][H] bf16
    bf16_t* __restrict__ h2buf,
    bf16_t* __restrict__ enc,         // [B,T,H] bf16
    float*  __restrict__ outl,        // [B,H] fp32
    unsigned* __restrict__ bar)
{
    __shared__ bf16_t wlds[64 * LPAD_];  // 132096 B

    const int blk  = blockIdx.x;
    const int is2  = (blk >= 128);
    const int wave = threadIdx.x >> 6;
    const int lane = threadIdx.x & 63;
    const int ln15 = lane & 15;
    const int quad = lane >> 4;
    const int bw   = wave * 16;

    unsigned* grp  = is2 ? (bar + 512) : bar;   // per-(block,wave) stamp words
    const int gidx = is2 ? (blk - 128) : blk;
    const int gn   = is2 ? 64 : 128;
    unsigned* flag = bar + 992;                 // timeout diagnostic

    int u0;
    if (!is2) {
        u0 = blk * 8;
        for (int i = threadIdx.x; i < 2 * 32 * 128; i += 256) {
            int mat = i >> 12;
            int rem = i & 4095;
            int n = rem >> 7;
            int kc = (rem & 127) * 8;
            int gate = n >> 3, unit = n & 7;
            const float* src = (mat ? whh1 : wih1) + (size_t)(gate * 1024 + u0 + unit) * H_ + kc;
            float4 f0 = *(const float4*)(src);
            float4 f1 = *(const float4*)(src + 4);
            bf16x8 w;
            w[0] = (bf16_t)f0.x; w[1] = (bf16_t)f0.y; w[2] = (bf16_t)f0.z; w[3] = (bf16_t)f0.w;
            w[4] = (bf16_t)f1.x; w[5] = (bf16_t)f1.y; w[6] = (bf16_t)f1.z; w[7] = (bf16_t)f1.w;
            *(bf16x8*)&wlds[(mat * 32 + n) * LPAD_ + kc] = w;
        }
        // zero-init h1 buf0 (write-through so it's visible without fences)
        for (int i = threadIdx.x; i < 64 * 4; i += 256)
            atom_store_u32((unsigned*)h1buf + (size_t)(i >> 2) * (H_ / 2) + (u0 >> 1) + (i & 3), 0u);
    } else {
        u0 = (blk - 128) * 16;
        for (int i = threadIdx.x; i < 64 * 128; i += 256) {
            int n = i >> 7;
            int kc = (i & 127) * 8;
            int gate = n >> 4, unit = n & 15;
            const float* src = whh2 + (size_t)(gate * 1024 + u0 + unit) * H_ + kc;
            float4 f0 = *(const float4*)(src);
            float4 f1 = *(const float4*)(src + 4);
            bf16x8 w;
            w[0] = (bf16_t)f0.x; w[1] = (bf16_t)f0.y; w[2] = (bf16_t)f0.z; w[3] = (bf16_t)f0.w;
            w[4] = (bf16_t)f1.x; w[5] = (bf16_t)f1.y; w[6] = (bf16_t)f1.z; w[7] = (bf16_t)f1.w;
            *(bf16x8*)&wlds[n * LPAD_ + kc] = w;
        }
        for (int i = threadIdx.x; i < 64 * 8; i += 256)
            atom_store_u32((unsigned*)h2buf + (size_t)(i >> 3) * (H_ / 2) + (u0 >> 1) + (i & 7), 0u);
    }

    // per-thread constants
    float bias0 = 0.f, bias1 = 0.f;
    float vreg[4][4];
    float b2reg[4];
    if (!is2) {
        int col0 = (ln15 < 8) ? (u0 + ln15) : (1024 + u0 + ln15 - 8);
        int col1 = (ln15 < 8) ? (2048 + u0 + ln15) : (3072 + u0 + ln15 - 8);
        bias0 = b1s[col0];
        bias1 = b1s[col1];
    } else {
        #pragma unroll
        for (int g = 0; g < 4; ++g) {
            int colg = g * 1024 + u0 + ln15;
            b2reg[g] = b2s[colg];
            #pragma unroll
            for (int r = 0; r < 4; ++r)
                vreg[g][r] = v[(size_t)(bw + quad * 4 + r) * G4_ + colg];
        }
    }

    // staging + zero-init visible: block barrier drains every wave's stores,
    // then each wave publishes stamp 1.
    __syncthreads();
    if (lane == 0)
        __hip_atomic_store(grp + (gidx * 4 + wave), 1u, __ATOMIC_RELAXED,
                           __HIP_MEMORY_SCOPE_AGENT);

    const bf16_t* hread  = is2 ? h2buf : h1buf;
    bf16_t*       hwrite = (is2 ? h2buf : h1buf) + B_ * H_;

    float c_st[4] = {0.f, 0.f, 0.f, 0.f};

    if (!is2) {
        unsigned stamp = 2;
        const bf16_t* xB0 = &wlds[(0 + ln15) * LPAD_ + quad * 8];
        const bf16_t* xB1 = &wlds[(16 + ln15) * LPAD_ + quad * 8];
        const bf16_t* hB0 = &wlds[(32 + ln15) * LPAD_ + quad * 8];
        const bf16_t* hB1 = &wlds[(48 + ln15) * LPAD_ + quad * 8];
        for (int t = 0; t < T_; ++t) {
            // ---- x-phase: asm-pipelined L2 loads (counted vmcnt); overlaps
            //      other blocks' publish->propagate. The 1 outstanding flag
            //      store retires first (vmcnt FIFO), counts stay valid. ----
            const bf16_t* xA = xb + ((size_t)(bw + ln15) * T_ + t) * F_ + quad * 8;
            f32x4 acc0 = {}, acc1 = {};
            {
                i32x4 xa[8], xc[8];
                loadl8(xa, xA, 0);
                loadl8(xc, xA, 1);
                WAITV(8);
                mfmah2(acc0, acc1, xa, xB0, xB1, 0);
                loadl8(xa, xA, 2);
                WAITV(8);
                mfmah2(acc0, acc1, xc, xB0, xB1, 1);
                loadl8(xc, xA, 3);
                WAITV(8);
                mfmah2(acc0, acc1, xa, xB0, xB1, 2);
                WAITV(0);
                mfmah2(acc0, acc1, xc, xB0, xB1, 3);
            }
            // ---- h[t-1] ready? (per-wave stamps, both halves concurrently) ----
            wave_wait(grp, gn, wave, lane, stamp - 1, flag);
            // ---- pipelined LLC h loads: 4 chunks x 8 frags, 2 in flight ----
            const bf16_t* hA = hread + (size_t)(bw + ln15) * H_ + quad * 8;
            {
                i32x4 ha[8], hc[8];
                loadh8(ha, hA, 0);
                loadh8(hc, hA, 1);
                WAITV(8);
                mfmah2(acc0, acc1, ha, hB0, hB1, 0);
                loadh8(ha, hA, 2);
                WAITV(8);
                mfmah2(acc0, acc1, hc, hB0, hB1, 1);
                loadh8(hc, hA, 3);
                WAITV(8);
                mfmah2(acc0, acc1, ha, hB0, hB1, 2);
                WAITV(0);
                mfmah2(acc0, acc1, hc, hB0, hB1, 3);
            }
            float out_h[4];
            #pragma unroll
            for (int r = 0; r < 4; ++r) {
                int b = bw + quad * 4 + r;
                float p0 = acc0[r] + bias0;          // i (ln15<8) or f (ln15>=8)
                float p1 = acc1[r] + bias1;          // g or o
                float q0 = __shfl_xor(p0, 8);
                float q1 = __shfl_xor(p1, 8);
                float ig = (ln15 < 8) ? p0 : q0;
                float fg = (ln15 < 8) ? q0 : p0;
                float gg = (ln15 < 8) ? p1 : q1;
                float og = (ln15 < 8) ? q1 : p1;
                ig = sig_fast(ig); fg = sig_fast(fg);
                gg = tanh_fast(gg); og = sig_fast(og);
                float c = fg * c_st[r] + ig * gg;
                c_st[r] = c;
                float h = og * tanh_fast(c);
                out_h[r] = h;
                unsigned hv = bf16_bits(h);
                unsigned pv = __shfl_xor(hv, 1);     // partner unit's h (ln15 xor 1)
                if ((ln15 & 1) == 0 && ln15 < 8)
                    atom_store_u32((unsigned*)hwrite + (size_t)b * (H_ / 2) + ((u0 + ln15) >> 1),
                                   hv | (pv << 16));
            }
            wave_publish(grp, gidx, wave, lane, stamp);
            if (t == T_ - 1 && ln15 < 8) {
                #pragma unroll
                for (int r = 0; r < 4; ++r)
                    outl[(size_t)(bw + quad * 4 + r) * H_ + u0 + ln15] = out_h[r];
            }
            stamp++;
            bf16_t* tmp = (bf16_t*)hread; hread = hwrite; hwrite = tmp;
        }
    } else {
        unsigned stamp = 2;
        const bf16_t* B0 = &wlds[(0 * 16 + ln15) * LPAD_ + quad * 8];
        const bf16_t* B1 = &wlds[(1 * 16 + ln15) * LPAD_ + quad * 8];
        const bf16_t* B2 = &wlds[(2 * 16 + ln15) * LPAD_ + quad * 8];
        const bf16_t* B3 = &wlds[(3 * 16 + ln15) * LPAD_ + quad * 8];
        for (int t = 0; t < T_; ++t) {
            // prefetch this step's ct scalars before the wait (cached loads)
            float cts_r[4];
            #pragma unroll
            for (int r = 0; r < 4; ++r) cts_r[r] = ct[(bw + quad * 4 + r) * T_ + t];
            wave_wait(grp, gn, wave, lane, stamp - 1, flag);
            const bf16_t* hA = hread + (size_t)(bw + ln15) * H_ + quad * 8;
            f32x4 acc[4] = {};
            {
                i32x4 ha[8], hc[8];
                loadh8(ha, hA, 0);
                loadh8(hc, hA, 1);
                WAITV(8);
                mfmah4(acc, ha, B0, B1, B2, B3, 0);
                loadh8(ha, hA, 2);
                WAITV(8);
                mfmah4(acc, hc, B0, B1, B2, B3, 1);
                loadh8(hc, hA, 3);
                WAITV(8);
                mfmah4(acc, ha, B0, B1, B2, B3, 2);
                WAITV(0);
                mfmah4(acc, hc, B0, B1, B2, B3, 3);
            }
            unsigned word_r[4];
            #pragma unroll
            for (int r = 0; r < 4; ++r) {
                int b = bw + quad * 4 + r;
                float cts = cts_r[r];
                float ig = sig_fast(acc[0][r] + cts * vreg[0][r] + b2reg[0]);
                float fg = sig_fast(acc[1][r] + cts * vreg[1][r] + b2reg[1]);
                float gg = tanh_fast(acc[2][r] + cts * vreg[2][r] + b2reg[2]);
                float og = sig_fast(acc[3][r] + cts * vreg[3][r] + b2reg[3]);
                float c = fg * c_st[r] + ig * gg;
                c_st[r] = c;
                float h = og * tanh_fast(c);
                unsigned hv = bf16_bits(h);
                unsigned pv = __shfl_xor(hv, 1);
                word_r[r] = hv | (pv << 16);
                if ((ln15 & 1) == 0)
                    atom_store_u32((unsigned*)hwrite + (size_t)b * (H_ / 2) + ((u0 + ln15) >> 1),
                                   word_r[r]);
            }
            wave_publish(grp, gidx, wave, lane, stamp);
            // enc stores AFTER the flag publish: not part of the protocol
            // (visible via end-of-kernel release), keeps them out of the drain.
            if ((ln15 & 1) == 0) {
                #pragma unroll
                for (int r = 0; r < 4; ++r) {
                    int b = bw + quad * 4 + r;
                    *((unsigned*)enc + ((size_t)b * T_ + t) * (H_ / 2) + ((u0 + ln15) >> 1)) = word_r[r];
                }
            }
            stamp++;
            bf16_t* tmp = (bf16_t*)hread; hread = hwrite; hwrite = tmp;
        }
    }
}

// ---------------- attention epilogue ----------------

__global__ __launch_bounds__(256) void p1_kernel(const bf16_t* __restrict__ enc,
                                                 float* __restrict__ Msm, float* __restrict__ Ssm) {
    int b = blockIdx.x;
    #pragma unroll
    for (int j = 0; j < 4; ++j) {
        int u = threadIdx.x + j * 256;
        const bf16_t* e = enc + (size_t)b * T_ * H_ + u;
        float m = -1e30f;
        for (int t = 0; t < T_; ++t) m = fmaxf(m, (float)e[(size_t)t * H_]);
        float s = 0.f;
        for (int t = 0; t < T_; ++t) s += __expf((float)e[(size_t)t * H_] - m);
        Msm[b * H_ + u] = m;
        Ssm[b * H_ + u] = s;
    }
}

__global__ __launch_bounds__(256) void p2_kernel(
    const bf16_t* __restrict__ enc, const float* __restrict__ Msm, const float* __restrict__ Ssm,
    const float* __restrict__ outl, const float* __restrict__ w_attn,
    bf16_t* __restrict__ saa, float* __restrict__ tapre) {
    int row = blockIdx.x;   // b*T+t
    int b = row >> 8;
    const bf16_t* erow = enc + (size_t)row * H_;
    float tsum = 0.f;
    for (int u = threadIdx.x; u < H_; u += 256) {
        float e = (float)erow[u];
        float sp = __expf(e - Msm[b * H_ + u]) / Ssm[b * H_ + u];
        saa[(size_t)row * H_ + u] = (bf16_t)(outl[b * H_ + u] * (sp + 1.f));
        tsum += tanh_fast(e) * w_attn[u];
    }
    tsum = waveReduceSum(tsum);
    __shared__ float red[4];
    if ((threadIdx.x & 63) == 0) red[threadIdx.x >> 6] = tsum;
    __syncthreads();
    if (threadIdx.x == 0) tapre[row] = red[0] + red[1] + red[2] + red[3];
}

// final: det = sigmoid(relu(r1)@w2 + b2); out = det*(1+sigmoid(tapre+b_attn))  [fp32 out]
__global__ __launch_bounds__(256) void p4_kernel(
    const float* __restrict__ r1, const float* __restrict__ w2, const float* __restrict__ b2,
    const float* __restrict__ tapre, const float* __restrict__ b_attn,
    const unsigned* __restrict__ flag, float* __restrict__ out) {
    int row = blockIdx.x * 4 + (threadIdx.x >> 6);
    int lane = threadIdx.x & 63;
    float vsum = fmaxf(r1[(size_t)row * 64 + lane], 0.f) * w2[lane];
    vsum = waveReduceSum(vsum);
    if (lane == 0) {
        float det = sig_fast(vsum + b2[0]);
        float ta = sig_fast(tapre[row] + b_attn[0]);
        out[row] = det * (1.f + ta) + 1000.f * (float)(*flag);
    }
}

// ---------------- launcher ----------------

extern "C" void kernel_launch(void* const* d_in, const int* in_sizes, int n_in,
                              void* d_out, int out_size, void* d_ws, size_t ws_size,
                              hipStream_t stream) {
    const float* x      = (const float*)d_in[0];
    const float* W_ih1  = (const float*)d_in[1];
    const float* W_hh1  = (const float*)d_in[2];
    const float* b_ih1  = (const float*)d_in[3];
    const float* b_hh1  = (const float*)d_in[4];
    const float* W_ih2  = (const float*)d_in[5];
    const float* W_hh2  = (const float*)d_in[6];
    const float* b_ih2  = (const float*)d_in[7];
    const float* b_hh2  = (const float*)d_in[8];
    const float* w_attn = (const float*)d_in[9];
    const float* b_attn = (const float*)d_in[10];
    const float* w1     = (const float*)d_in[11];
    const float* b1     = (const float*)d_in[12];
    const float* w2     = (const float*)d_in[13];
    const float* b2     = (const float*)d_in[14];

    char* ws = (char*)d_ws;
    size_t off = 0;
    auto alloc = [&](size_t bytes) { size_t r = off; off = (off + bytes + 255) & ~(size_t)255; return r; };

    size_t o_bar  = alloc(4096);                      // per-(block,wave) stamps + diag flag
    size_t o_wih2 = alloc((size_t)G4_ * H_ * 2);      // 8 MB bf16 (for v-gemm)
    size_t o_xb   = alloc((size_t)B_ * T_ * F_ * 2);  // 32 MB
    size_t o_b1s  = alloc(G4_ * 4);
    size_t o_b2s  = alloc(G4_ * 4);
    size_t o_ct   = alloc(B_ * T_ * 4);
    size_t o_ccb  = alloc(B_ * F_ * 2);
    size_t o_v    = alloc((size_t)B_ * G4_ * 4);      // 1 MB
    size_t o_h1   = alloc(2 * B_ * H_ * 2);
    size_t o_h2   = alloc(2 * B_ * H_ * 2);
    size_t o_outl = alloc(B_ * H_ * 4);
    size_t o_w1t  = alloc(64 * H_ * 2);
    size_t o_msm  = alloc(B_ * H_ * 4);
    size_t o_ssm  = alloc(B_ * H_ * 4);
    size_t o_tap  = alloc(B_ * T_ * 4);
    size_t o_enc  = alloc((size_t)B_ * T_ * H_ * 2);  // 32 MB bf16
    size_t o_saa  = o_xb;                             // alias: xb dead after recurrence
    size_t o_r1   = o_enc;                            // alias: enc dead after p2

    if (ws_size < off) return;  // fail loudly as absmax mismatch, never a fault

    unsigned* bar  = (unsigned*)(ws + o_bar);
    bf16_t* wih2b  = (bf16_t*)(ws + o_wih2);
    bf16_t* xb     = (bf16_t*)(ws + o_xb);
    float*  b1s    = (float*)(ws + o_b1s);
    float*  b2s    = (float*)(ws + o_b2s);
    float*  ctp    = (float*)(ws + o_ct);
    bf16_t* ccb    = (bf16_t*)(ws + o_ccb);
    float*  vbuf   = (float*)(ws + o_v);
    bf16_t* h1     = (bf16_t*)(ws + o_h1);
    bf16_t* h2     = (bf16_t*)(ws + o_h2);
    float*  outl   = (float*)(ws + o_outl);
    bf16_t* w1t    = (bf16_t*)(ws + o_w1t);
    float*  msm    = (float*)(ws + o_msm);
    float*  ssm    = (float*)(ws + o_ssm);
    float*  tap    = (float*)(ws + o_tap);
    bf16_t* encp   = (bf16_t*)(ws + o_enc);
    bf16_t* saa    = (bf16_t*)(ws + o_saa);
    float*  r1     = (float*)(ws + o_r1);

    hipMemsetAsync(ws + o_bar, 0, 4096, stream);

    int n = G4_ * H_;
    cast_kernel<<<(n + 255) / 256, 256, 0, stream>>>(W_ih2, wih2b, n);
    n = B_ * T_ * F_;
    cast_kernel<<<(n + 255) / 256, 256, 0, stream>>>(x, xb, n);
    bias_sum_kernel<<<16, 256, 0, stream>>>(b_ih1, b_hh1, b1s, G4_);
    bias_sum_kernel<<<16, 256, 0, stream>>>(b_ih2, b_hh2, b2s, G4_);
    cov1_kernel<<<B_ * T_ / 4, 256, 0, stream>>>(x, ctp);
    cov2_kernel<<<B_, 256, 0, stream>>>(x, ccb);
    w1t_kernel<<<256, 256, 0, stream>>>(w1, w1t);

    // v = cov_chan * Wih2^T (fp32 out)
    gemm_bt_kernel<<<dim3(G4_ / 64, 1), 256, 0, stream>>>(ccb, wih2b, nullptr, vbuf, B_, G4_, H_);

    lstm_recur_kernel<<<NBLK_, 256, 0, stream>>>(
        xb, ctp, vbuf, b1s, b2s, W_ih1, W_hh1, W_hh2, h1, h2, encp, outl, bar);

    p1_kernel<<<B_, 256, 0, stream>>>(encp, msm, ssm);
    p2_kernel<<<B_ * T_, 256, 0, stream>>>(encp, msm, ssm, outl, w_attn, saa, tap);
    // r1 = saa * w1T^T + b1 (fp32 out)
    gemm_bt_kernel<<<dim3(1, B_ * T_ / 128), 256, 0, stream>>>(saa, w1t, b1, r1, B_ * T_, 64, H_);
    p4_kernel<<<B_ * T_ / 4, 256, 0, stream>>>(r1, w2, b2, tap, b_attn, bar + 992, (float*)d_out);

    (void)in_sizes; (void)n_in; (void)out_size;
}

// Round 7
// 2679.054 us; speedup vs baseline: 2.0972x; 1.1820x over previous
//
#include <hip/hip_runtime.h>

typedef __bf16 bf16_t;
typedef __bf16 bf16x8 __attribute__((ext_vector_type(8)));
typedef float f32x4 __attribute__((ext_vector_type(4)));
typedef int i32x4 __attribute__((ext_vector_type(4)));
typedef unsigned long long u64;

#define B_ 64
#define T_ 256
#define F_ 1024
#define H_ 1024
#define G4_ 4096
#define NBLK_ 192
#define LPAD_ 1032   // LDS row stride (elems)

#define MFMA16 __builtin_amdgcn_mfma_f32_16x16x32_bf16

__device__ __forceinline__ float sig_fast(float x) { return 1.f / (1.f + __expf(-x)); }
__device__ __forceinline__ float tanh_fast(float x) {
    float e = __expf(2.f * x);
    return 1.f - 2.f / (e + 1.f);
}
__device__ __forceinline__ float waveReduceSum(float v) {
    #pragma unroll
    for (int off = 32; off > 0; off >>= 1) v += __shfl_xor(v, off);
    return v;
}

// ---- agent-coherent (sc0 sc1) helpers: per-instruction coherence, NO cache fences ----
__device__ __forceinline__ void atom_store_u32(unsigned* p, unsigned v) {
    __hip_atomic_store(p, v, __ATOMIC_RELAXED, __HIP_MEMORY_SCOPE_AGENT);
}
// 16B LLC-direct load (bypasses stale L1/L2). Result NOT valid until an
// explicit s_waitcnt vmcnt(N) retires it — callers use WAITV below.
__device__ __forceinline__ i32x4 llc_load16(const bf16_t* p) {
    i32x4 r;
    asm volatile("global_load_dwordx4 %0, %1, off sc0 sc1"
                 : "=&v"(r) : "v"(p) : "memory");
    return r;
}
// 16B normally-cached load (L1/L2 path) with the same manual-wait contract.
__device__ __forceinline__ i32x4 l2_load16(const bf16_t* p) {
    i32x4 r;
    asm volatile("global_load_dwordx4 %0, %1, off"
                 : "=&v"(r) : "v"(p) : "memory");
    return r;
}
#define WAITV(N) do { asm volatile("s_waitcnt vmcnt(" #N ")" ::: "memory"); \
                      __builtin_amdgcn_sched_barrier(0); } while (0)

__device__ __forceinline__ unsigned bf16_bits(float f) {
    unsigned short s = __builtin_bit_cast(unsigned short, (bf16_t)f);
    return (unsigned)s;
}

// ---- heater: 48 independent v_fmac under the poll-load latency ----
#define H4_ "v_fmac_f32 %0, %4, %5\n\tv_fmac_f32 %1, %4, %5\n\tv_fmac_f32 %2, %4, %5\n\tv_fmac_f32 %3, %4, %5\n\t"
#define H16_ H4_ H4_ H4_ H4_
#define H48_ H16_ H16_ H16_
#define HEAT() asm volatile(H48_ : "+v"(hh0), "+v"(hh1), "+v"(hh2), "+v"(hh3) \
                            : "v"(hm), "v"(hb))

// ---- per-wave flag barrier (publish / wait), fence-free, no __syncthreads ----
__device__ __forceinline__ void wave_publish(unsigned* grp, int gidx, int wave, int lane,
                                             unsigned stamp) {
    asm volatile("s_waitcnt vmcnt(0)" ::: "memory");
    if (lane == 0)
        __hip_atomic_store(grp + (gidx * 4 + wave), stamp, __ATOMIC_RELAXED,
                           __HIP_MEMORY_SCOPE_AGENT);
}

__device__ __forceinline__ void wave_wait(const unsigned* grp, int gn, int wave, int lane,
                                          unsigned stamp, unsigned* flag) {
    const unsigned* p0 = grp + (lane * 4 + wave);
    const unsigned* p1 = grp + ((lane + 64) * 4 + wave);
    const bool two = (gn > 64);
    float hh0 = 1.f + lane, hh1 = 2.f, hh2 = 3.f, hh3 = 4.f;
    const float hm = 1.0001f, hb = 0.5f;
    int spins = 0;
    for (;;) {
        unsigned v0, v1 = 0xffffffffu;
        asm volatile("global_load_dword %0, %1, off sc0 sc1"
                     : "=&v"(v0) : "v"(p0) : "memory");
        if (two)
            asm volatile("global_load_dword %0, %1, off sc0 sc1"
                         : "=&v"(v1) : "v"(p1) : "memory");
        HEAT();
        asm volatile("s_waitcnt vmcnt(0)" : "+v"(v0), "+v"(v1) :: "memory");
        if (v0 >= stamp && v1 >= stamp) break;
        ++spins;
        if (spins > 4096) __builtin_amdgcn_s_sleep(1);  // degrade gracefully
        if ((spins & 31) == 0) {
            if (__hip_atomic_load(flag, __ATOMIC_RELAXED, __HIP_MEMORY_SCOPE_AGENT)) break;
            if (spins > 2000000) {  // latch diagnostic, never hang
                __hip_atomic_fetch_or(flag, 1u, __ATOMIC_RELAXED, __HIP_MEMORY_SCOPE_AGENT);
                break;
            }
        }
    }
}

// ---- pipelined GEMM-phase building blocks ----
// h layout: [kblk 0..127][row 0..63][8 units] bf16 -> 16B per (kblk,row).
// Consumer lane (ln15,quad) reads kblk = c*32+j*4+quad, row = bw+ln15:
// 16 lanes = 256B CONTIGUOUS per quad (4 line-touches/instr vs 16 before).
__device__ __forceinline__ void loadh8(i32x4* d, const bf16_t* hbase, int c) {
    #pragma unroll
    for (int j = 0; j < 8; ++j) d[j] = llc_load16(hbase + (size_t)(c * 8 + j) * 2048);
}
// xb layout: [t][b][f] -> per (ln15) row contiguous 2KB, shared across blocks.
__device__ __forceinline__ void loadl8(i32x4* d, const bf16_t* base, int c) {
    #pragma unroll
    for (int j = 0; j < 8; ++j) d[j] = l2_load16(base + (c * 8 + j) * 32);
}
__device__ __forceinline__ void mfmah2(f32x4& a0, f32x4& a1, const i32x4* hf,
                                       const bf16_t* B0, const bf16_t* B1, int c) {
    #pragma unroll
    for (int j = 0; j < 8; ++j) {
        bf16x8 h8 = __builtin_bit_cast(bf16x8, hf[j]);
        a0 = MFMA16(h8, *(const bf16x8*)(B0 + (c * 8 + j) * 32), a0, 0, 0, 0);
        a1 = MFMA16(h8, *(const bf16x8*)(B1 + (c * 8 + j) * 32), a1, 0, 0, 0);
    }
}
__device__ __forceinline__ void mfmah4(f32x4* acc, const i32x4* hf,
                                       const bf16_t* B0, const bf16_t* B1,
                                       const bf16_t* B2, const bf16_t* B3, int c) {
    #pragma unroll
    for (int j = 0; j < 8; ++j) {
        bf16x8 h8 = __builtin_bit_cast(bf16x8, hf[j]);
        acc[0] = MFMA16(h8, *(const bf16x8*)(B0 + (c * 8 + j) * 32), acc[0], 0, 0, 0);
        acc[1] = MFMA16(h8, *(const bf16x8*)(B1 + (c * 8 + j) * 32), acc[1], 0, 0, 0);
        acc[2] = MFMA16(h8, *(const bf16x8*)(B2 + (c * 8 + j) * 32), acc[2], 0, 0, 0);
        acc[3] = MFMA16(h8, *(const bf16x8*)(B3 + (c * 8 + j) * 32), acc[3], 0, 0, 0);
    }
}

// ---------------- small prep kernels ----------------

__global__ void cast_kernel(const float* __restrict__ src, bf16_t* __restrict__ dst, int n) {
    int i = blockIdx.x * 256 + threadIdx.x;
    if (i < n) dst[i] = (bf16_t)src[i];
}

// x [b][t][f] fp32 -> xb [t][b][f] bf16 (transposed for coalesced recurrence reads)
__global__ void xt_kernel(const float* __restrict__ x, bf16_t* __restrict__ xb) {
    int o = blockIdx.x * 256 + threadIdx.x;   // o = t*B*F + b*F + f
    int f = o & (F_ - 1);
    int b = (o >> 10) & (B_ - 1);
    int t = o >> 16;
    xb[o] = (bf16_t)x[((size_t)b * T_ + t) * F_ + f];
}

__global__ void bias_sum_kernel(const float* __restrict__ a, const float* __restrict__ b,
                                float* __restrict__ dst, int n) {
    int i = blockIdx.x * 256 + threadIdx.x;
    if (i < n) dst[i] = a[i] + b[i];
}

// w1 [1024,64] -> w1T bf16 [64,1024]
__global__ void w1t_kernel(const float* __restrict__ w1, bf16_t* __restrict__ w1T) {
    int i = blockIdx.x * 256 + threadIdx.x;  // 65536
    int j = i >> 10, u = i & 1023;
    w1T[i] = (bf16_t)w1[u * 64 + j];
}

// cov_temp[b,t] = (b%32==31)?0 : max(0, (sum_f x^2 - (sum_f x)^2/F)/T)
__global__ __launch_bounds__(256) void cov1_kernel(const float* __restrict__ x, float* __restrict__ ct) {
    int row = blockIdx.x * 4 + (threadIdx.x >> 6);  // b*T+t
    int lane = threadIdx.x & 63;
    const float* xr = x + (size_t)row * F_;
    float s1 = 0.f, s2 = 0.f;
    for (int f = lane; f < F_; f += 64) { float v = xr[f]; s1 += v; s2 += v * v; }
    s1 = waveReduceSum(s1);
    s2 = waveReduceSum(s2);
    if (lane == 0) {
        int b = row >> 8;
        float c = (s2 - s1 * s1 * (1.f / F_)) * (1.f / T_);
        ct[row] = ((b & 31) == 31) ? 0.f : fmaxf(c, 0.f);
    }
}

// cov_chan[b,f] (bf16) = (b%32==31)?0 : max(0, (sum_t x^2 - (sum_t x)^2/T)/F)
__global__ __launch_bounds__(256) void cov2_kernel(const float* __restrict__ x,
                                                   bf16_t* __restrict__ ccb) {
    int b = blockIdx.x;
    #pragma unroll
    for (int j = 0; j < 4; ++j) {
        int f = threadIdx.x + j * 256;
        float s1 = 0.f, s2 = 0.f;
        for (int t = 0; t < T_; ++t) {
            float v = x[((size_t)b * T_ + t) * F_ + f];
            s1 += v; s2 += v * v;
        }
        float c = (s2 - s1 * s1 * (1.f / T_)) * (1.f / F_);
        if ((b & 31) == 31) c = 0.f;
        ccb[b * F_ + f] = (bf16_t)fmaxf(c, 0.f);
    }
}

// ---------------- generic MFMA GEMM: C[M,N] = A[M,K] * B[N,K]^T (+bias) ----------------
__global__ __launch_bounds__(256) void gemm_bt_kernel(
    const bf16_t* __restrict__ A, const bf16_t* __restrict__ B,
    const float* __restrict__ bias, float* __restrict__ C,
    int M, int N, int K)
{
    const int wave = threadIdx.x >> 6;
    const int lane = threadIdx.x & 63;
    const int ln15 = lane & 15;
    const int quad = lane >> 4;
    const int n_base = blockIdx.x * 64;
    const int m_wave = blockIdx.y * 128 + wave * 32;

    f32x4 acc[2][4] = {};

    int rowA0 = m_wave + ln15;       if (rowA0 >= M) rowA0 = M - 1;
    int rowA1 = m_wave + 16 + ln15;  if (rowA1 >= M) rowA1 = M - 1;
    const bf16_t* Arow0 = A + (size_t)rowA0 * K + quad * 8;
    const bf16_t* Arow1 = A + (size_t)rowA1 * K + quad * 8;
    const bf16_t* Brow0 = B + (size_t)(n_base + 0 * 16 + ln15) * K + quad * 8;
    const bf16_t* Brow1 = B + (size_t)(n_base + 1 * 16 + ln15) * K + quad * 8;
    const bf16_t* Brow2 = B + (size_t)(n_base + 2 * 16 + ln15) * K + quad * 8;
    const bf16_t* Brow3 = B + (size_t)(n_base + 3 * 16 + ln15) * K + quad * 8;

    for (int k0 = 0; k0 < K; k0 += 32) {
        bf16x8 a0 = *(const bf16x8*)(Arow0 + k0);
        bf16x8 a1 = *(const bf16x8*)(Arow1 + k0);
        bf16x8 b0 = *(const bf16x8*)(Brow0 + k0);
        bf16x8 b1 = *(const bf16x8*)(Brow1 + k0);
        bf16x8 b2 = *(const bf16x8*)(Brow2 + k0);
        bf16x8 b3 = *(const bf16x8*)(Brow3 + k0);
        acc[0][0] = MFMA16(a0, b0, acc[0][0], 0, 0, 0);
        acc[0][1] = MFMA16(a0, b1, acc[0][1], 0, 0, 0);
        acc[0][2] = MFMA16(a0, b2, acc[0][2], 0, 0, 0);
        acc[0][3] = MFMA16(a0, b3, acc[0][3], 0, 0, 0);
        acc[1][0] = MFMA16(a1, b0, acc[1][0], 0, 0, 0);
        acc[1][1] = MFMA16(a1, b1, acc[1][1], 0, 0, 0);
        acc[1][2] = MFMA16(a1, b2, acc[1][2], 0, 0, 0);
        acc[1][3] = MFMA16(a1, b3, acc[1][3], 0, 0, 0);
    }

    #pragma unroll
    for (int s = 0; s < 2; ++s) {
        #pragma unroll
        for (int g = 0; g < 4; ++g) {
            int col = n_base + g * 16 + ln15;
            float bv = bias ? bias[col] : 0.f;
            #pragma unroll
            for (int r = 0; r < 4; ++r) {
                int row = m_wave + s * 16 + quad * 4 + r;
                if (row < M) C[(size_t)row * N + col] = acc[s][g][r] + bv;
            }
        }
    }
}

// ---------------- persistent dual-LSTM recurrence ----------------
// blocks 0..127:  LSTM1, 8 units each; blocks 128..191: LSTM2, 16 units each.
// h exchange layout: [kblk][row][8units] bf16 — producer block writes one
// contiguous 1KB region; consumer loads are 256B-contiguous per quad.
// Stamps per (block,wave); no __syncthreads in the loop.
__global__ __launch_bounds__(256, 1) void lstm_recur_kernel(
    const bf16_t* __restrict__ xb,    // [T,B,F] bf16 (transposed)
    const float*  __restrict__ ct,    // [B,T]
    const float*  __restrict__ v,     // [B,4096] fp32
    const float*  __restrict__ b1s,   // [4096]
    const float*  __restrict__ b2s,   // [4096]
    const float*  __restrict__ wih1,  // [4096,1024] fp32
    const float*  __restrict__ whh1,  // [4096,1024] fp32
    const float*  __restrict__ whh2,  // [4096,1024] fp32
    bf16_t* __restrict__ h1buf,       // [2][128 kblk][64 row][8] bf16
    bf16_t* __restrict__ h2buf,
    bf16_t* __restrict__ enc,         // [B,T,H] bf16
    float*  __restrict__ outl,        // [B,H] fp32
    unsigned* __restrict__ bar)
{
    __shared__ bf16_t wlds[64 * LPAD_];  // 132096 B

    const int blk  = blockIdx.x;
    const int is2  = (blk >= 128);
    const int wave = threadIdx.x >> 6;
    const int lane = threadIdx.x & 63;
    const int ln15 = lane & 15;
    const int quad = lane >> 4;
    const int bw   = wave * 16;

    unsigned* grp  = is2 ? (bar + 512) : bar;   // packed per-(block,wave) stamps
    const int gidx = is2 ? (blk - 128) : blk;
    const int gn   = is2 ? 64 : 128;
    unsigned* flag = bar + 992;                 // timeout diagnostic

    int u0;
    if (!is2) {
        u0 = blk * 8;
        for (int i = threadIdx.x; i < 2 * 32 * 128; i += 256) {
            int mat = i >> 12;
            int rem = i & 4095;
            int n = rem >> 7;
            int kc = (rem & 127) * 8;
            int gate = n >> 3, unit = n & 7;
            const float* src = (mat ? whh1 : wih1) + (size_t)(gate * 1024 + u0 + unit) * H_ + kc;
            float4 f0 = *(const float4*)(src);
            float4 f1 = *(const float4*)(src + 4);
            bf16x8 w;
            w[0] = (bf16_t)f0.x; w[1] = (bf16_t)f0.y; w[2] = (bf16_t)f0.z; w[3] = (bf16_t)f0.w;
            w[4] = (bf16_t)f1.x; w[5] = (bf16_t)f1.y; w[6] = (bf16_t)f1.z; w[7] = (bf16_t)f1.w;
            *(bf16x8*)&wlds[(mat * 32 + n) * LPAD_ + kc] = w;
        }
        // zero-init h1 buf0, own kblk region (write-through, visible sans fences)
        for (int i = threadIdx.x; i < 256; i += 256)
            atom_store_u32((unsigned*)h1buf + blk * 256 + i, 0u);
    } else {
        u0 = (blk - 128) * 16;
        for (int i = threadIdx.x; i < 64 * 128; i += 256) {
            int n = i >> 7;
            int kc = (i & 127) * 8;
            int gate = n >> 4, unit = n & 15;
            const float* src = whh2 + (size_t)(gate * 1024 + u0 + unit) * H_ + kc;
            float4 f0 = *(const float4*)(src);
            float4 f1 = *(const float4*)(src + 4);
            bf16x8 w;
            w[0] = (bf16_t)f0.x; w[1] = (bf16_t)f0.y; w[2] = (bf16_t)f0.z; w[3] = (bf16_t)f0.w;
            w[4] = (bf16_t)f1.x; w[5] = (bf16_t)f1.y; w[6] = (bf16_t)f1.z; w[7] = (bf16_t)f1.w;
            *(bf16x8*)&wlds[n * LPAD_ + kc] = w;
        }
        for (int i = threadIdx.x; i < 512; i += 256)
            atom_store_u32((unsigned*)h2buf + 2 * gidx * 256 + i, 0u);
    }

    // per-thread constants
    float bias0 = 0.f, bias1 = 0.f;
    float vreg[4][4];
    float b2reg[4];
    if (!is2) {
        int col0 = (ln15 < 8) ? (u0 + ln15) : (1024 + u0 + ln15 - 8);
        int col1 = (ln15 < 8) ? (2048 + u0 + ln15) : (3072 + u0 + ln15 - 8);
        bias0 = b1s[col0];
        bias1 = b1s[col1];
    } else {
        #pragma unroll
        for (int g = 0; g < 4; ++g) {
            int colg = g * 1024 + u0 + ln15;
            b2reg[g] = b2s[colg];
            #pragma unroll
            for (int r = 0; r < 4; ++r)
                vreg[g][r] = v[(size_t)(bw + quad * 4 + r) * G4_ + colg];
        }
    }

    // staging + zero-init visible: block barrier drains, each wave publishes stamp 1.
    __syncthreads();
    if (lane == 0)
        __hip_atomic_store(grp + (gidx * 4 + wave), 1u, __ATOMIC_RELAXED,
                           __HIP_MEMORY_SCOPE_AGENT);

    const bf16_t* hread  = is2 ? h2buf : h1buf;
    bf16_t*       hwrite = (is2 ? h2buf : h1buf) + B_ * H_;

    float c_st[4] = {0.f, 0.f, 0.f, 0.f};

    if (!is2) {
        unsigned stamp = 2;
        const bf16_t* xB0 = &wlds[(0 + ln15) * LPAD_ + quad * 8];
        const bf16_t* xB1 = &wlds[(16 + ln15) * LPAD_ + quad * 8];
        const bf16_t* hB0 = &wlds[(32 + ln15) * LPAD_ + quad * 8];
        const bf16_t* hB1 = &wlds[(48 + ln15) * LPAD_ + quad * 8];
        const int hoff = quad * 512 + (bw + ln15) * 8;   // lane offset in kblk layout
        for (int t = 0; t < T_; ++t) {
            // ---- x-phase (transposed xb: contiguous per row, shared across blocks) ----
            const bf16_t* xA = xb + (size_t)t * B_ * F_ + (bw + ln15) * F_ + quad * 8;
            f32x4 acc0 = {}, acc1 = {};
            i32x4 xa[8], xc[8];
            loadl8(xa, xA, 0);
            loadl8(xc, xA, 1);
            WAITV(8);
            mfmah2(acc0, acc1, xa, xB0, xB1, 0);
            loadl8(xa, xA, 2);
            WAITV(8);
            mfmah2(acc0, acc1, xc, xB0, xB1, 1);
            loadl8(xc, xA, 3);
            WAITV(8);
            mfmah2(acc0, acc1, xa, xB0, xB1, 2);
            WAITV(0);                       // xc ready; keep for after the wait
            // ---- h[t-1] ready? ----
            wave_wait(grp, gn, wave, lane, stamp - 1, flag);
            // ---- issue h chunks 0/1, then final x-chunk MFMAs cover the LLC latency ----
            const bf16_t* hA = hread + hoff;
            i32x4 ha[8], hc[8];
            loadh8(ha, hA, 0);
            loadh8(hc, hA, 1);
            mfmah2(acc0, acc1, xc, xB0, xB1, 3);   // x chunk 3 (operands in regs)
            WAITV(8);
            mfmah2(acc0, acc1, ha, hB0, hB1, 0);
            loadh8(ha, hA, 2);
            WAITV(8);
            mfmah2(acc0, acc1, hc, hB0, hB1, 1);
            loadh8(hc, hA, 3);
            WAITV(8);
            mfmah2(acc0, acc1, ha, hB0, hB1, 2);
            WAITV(0);
            mfmah2(acc0, acc1, hc, hB0, hB1, 3);
            float out_h[4];
            #pragma unroll
            for (int r = 0; r < 4; ++r) {
                int b = bw + quad * 4 + r;
                float p0 = acc0[r] + bias0;          // i (ln15<8) or f (ln15>=8)
                float p1 = acc1[r] + bias1;          // g or o
                float q0 = __shfl_xor(p0, 8);
                float q1 = __shfl_xor(p1, 8);
                float ig = (ln15 < 8) ? p0 : q0;
                float fg = (ln15 < 8) ? q0 : p0;
                float gg = (ln15 < 8) ? p1 : q1;
                float og = (ln15 < 8) ? q1 : p1;
                ig = sig_fast(ig); fg = sig_fast(fg);
                gg = tanh_fast(gg); og = sig_fast(og);
                float c = fg * c_st[r] + ig * gg;
                c_st[r] = c;
                float h = og * tanh_fast(c);
                out_h[r] = h;
                unsigned hv = bf16_bits(h);
                unsigned pv = __shfl_xor(hv, 1);     // partner unit's h (ln15 xor 1)
                if ((ln15 & 1) == 0 && ln15 < 8)
                    atom_store_u32((unsigned*)hwrite + blk * 256 + b * 4 + (ln15 >> 1),
                                   hv | (pv << 16));
            }
            wave_publish(grp, gidx, wave, lane, stamp);
            if (t == T_ - 1 && ln15 < 8) {
                #pragma unroll
                for (int r = 0; r < 4; ++r)
                    outl[(size_t)(bw + quad * 4 + r) * H_ + u0 + ln15] = out_h[r];
            }
            stamp++;
            bf16_t* tmp = (bf16_t*)hread; hread = hwrite; hwrite = tmp;
        }
    } else {
        unsigned stamp = 2;
        const bf16_t* B0 = &wlds[(0 * 16 + ln15) * LPAD_ + quad * 8];
        const bf16_t* B1 = &wlds[(1 * 16 + ln15) * LPAD_ + quad * 8];
        const bf16_t* B2 = &wlds[(2 * 16 + ln15) * LPAD_ + quad * 8];
        const bf16_t* B3 = &wlds[(3 * 16 + ln15) * LPAD_ + quad * 8];
        const int hoff = quad * 512 + (bw + ln15) * 8;
        for (int t = 0; t < T_; ++t) {
            // prefetch this step's ct scalars before the wait (cached loads)
            float cts_r[4];
            #pragma unroll
            for (int r = 0; r < 4; ++r) cts_r[r] = ct[(bw + quad * 4 + r) * T_ + t];
            wave_wait(grp, gn, wave, lane, stamp - 1, flag);
            const bf16_t* hA = hread + hoff;
            f32x4 acc[4] = {};
            {
                i32x4 ha[8], hc[8];
                loadh8(ha, hA, 0);
                loadh8(hc, hA, 1);
                WAITV(8);
                mfmah4(acc, ha, B0, B1, B2, B3, 0);
                loadh8(ha, hA, 2);
                WAITV(8);
                mfmah4(acc, hc, B0, B1, B2, B3, 1);
                loadh8(hc, hA, 3);
                WAITV(8);
                mfmah4(acc, ha, B0, B1, B2, B3, 2);
                WAITV(0);
                mfmah4(acc, hc, B0, B1, B2, B3, 3);
            }
            unsigned word_r[4];
            #pragma unroll
            for (int r = 0; r < 4; ++r) {
                int b = bw + quad * 4 + r;
                float cts = cts_r[r];
                float ig = sig_fast(acc[0][r] + cts * vreg[0][r] + b2reg[0]);
                float fg = sig_fast(acc[1][r] + cts * vreg[1][r] + b2reg[1]);
                float gg = tanh_fast(acc[2][r] + cts * vreg[2][r] + b2reg[2]);
                float og = sig_fast(acc[3][r] + cts * vreg[3][r] + b2reg[3]);
                float c = fg * c_st[r] + ig * gg;
                c_st[r] = c;
                float h = og * tanh_fast(c);
                unsigned hv = bf16_bits(h);
                unsigned pv = __shfl_xor(hv, 1);
                word_r[r] = hv | (pv << 16);
                if ((ln15 & 1) == 0)
                    atom_store_u32((unsigned*)hwrite + (2 * gidx + (ln15 >> 3)) * 256
                                       + b * 4 + ((ln15 & 7) >> 1),
                                   word_r[r]);
            }
            wave_publish(grp, gidx, wave, lane, stamp);
            // enc stores AFTER the flag publish (drained by next wait, not protocol)
            if ((ln15 & 1) == 0) {
                #pragma unroll
                for (int r = 0; r < 4; ++r) {
                    int b = bw + quad * 4 + r;
                    *((unsigned*)enc + ((size_t)b * T_ + t) * (H_ / 2) + ((u0 + ln15) >> 1)) = word_r[r];
                }
            }
            stamp++;
            bf16_t* tmp = (bf16_t*)hread; hread = hwrite; hwrite = tmp;
        }
    }
}

// ---------------- attention epilogue ----------------

__global__ __launch_bounds__(256) void p1_kernel(const bf16_t* __restrict__ enc,
                                                 float* __restrict__ Msm, float* __restrict__ Ssm) {
    int b = blockIdx.x;
    #pragma unroll
    for (int j = 0; j < 4; ++j) {
        int u = threadIdx.x + j * 256;
        const bf16_t* e = enc + (size_t)b * T_ * H_ + u;
        float m = -1e30f;
        for (int t = 0; t < T_; ++t) m = fmaxf(m, (float)e[(size_t)t * H_]);
        float s = 0.f;
        for (int t = 0; t < T_; ++t) s += __expf((float)e[(size_t)t * H_] - m);
        Msm[b * H_ + u] = m;
        Ssm[b * H_ + u] = s;
    }
}

__global__ __launch_bounds__(256) void p2_kernel(
    const bf16_t* __restrict__ enc, const float* __restrict__ Msm, const float* __restrict__ Ssm,
    const float* __restrict__ outl, const float* __restrict__ w_attn,
    bf16_t* __restrict__ saa, float* __restrict__ tapre) {
    int row = blockIdx.x;   // b*T+t
    int b = row >> 8;
    const bf16_t* erow = enc + (size_t)row * H_;
    float tsum = 0.f;
    for (int u = threadIdx.x; u < H_; u += 256) {
        float e = (float)erow[u];
        float sp = __expf(e - Msm[b * H_ + u]) / Ssm[b * H_ + u];
        saa[(size_t)row * H_ + u] = (bf16_t)(outl[b * H_ + u] * (sp + 1.f));
        tsum += tanh_fast(e) * w_attn[u];
    }
    tsum = waveReduceSum(tsum);
    __shared__ float red[4];
    if ((threadIdx.x & 63) == 0) red[threadIdx.x >> 6] = tsum;
    __syncthreads();
    if (threadIdx.x == 0) tapre[row] = red[0] + red[1] + red[2] + red[3];
}

// final: det = sigmoid(relu(r1)@w2 + b2); out = det*(1+sigmoid(tapre+b_attn))  [fp32 out]
__global__ __launch_bounds__(256) void p4_kernel(
    const float* __restrict__ r1, const float* __restrict__ w2, const float* __restrict__ b2,
    const float* __restrict__ tapre, const float* __restrict__ b_attn,
    const unsigned* __restrict__ flag, float* __restrict__ out) {
    int row = blockIdx.x * 4 + (threadIdx.x >> 6);
    int lane = threadIdx.x & 63;
    float vsum = fmaxf(r1[(size_t)row * 64 + lane], 0.f) * w2[lane];
    vsum = waveReduceSum(vsum);
    if (lane == 0) {
        float det = sig_fast(vsum + b2[0]);
        float ta = sig_fast(tapre[row] + b_attn[0]);
        out[row] = det * (1.f + ta) + 1000.f * (float)(*flag);
    }
}

// ---------------- launcher ----------------

extern "C" void kernel_launch(void* const* d_in, const int* in_sizes, int n_in,
                              void* d_out, int out_size, void* d_ws, size_t ws_size,
                              hipStream_t stream) {
    const float* x      = (const float*)d_in[0];
    const float* W_ih1  = (const float*)d_in[1];
    const float* W_hh1  = (const float*)d_in[2];
    const float* b_ih1  = (const float*)d_in[3];
    const float* b_hh1  = (const float*)d_in[4];
    const float* W_ih2  = (const float*)d_in[5];
    const float* W_hh2  = (const float*)d_in[6];
    const float* b_ih2  = (const float*)d_in[7];
    const float* b_hh2  = (const float*)d_in[8];
    const float* w_attn = (const float*)d_in[9];
    const float* b_attn = (const float*)d_in[10];
    const float* w1     = (const float*)d_in[11];
    const float* b1     = (const float*)d_in[12];
    const float* w2     = (const float*)d_in[13];
    const float* b2     = (const float*)d_in[14];

    char* ws = (char*)d_ws;
    size_t off = 0;
    auto alloc = [&](size_t bytes) { size_t r = off; off = (off + bytes + 255) & ~(size_t)255; return r; };

    size_t o_bar  = alloc(4096);                      // per-(block,wave) stamps + diag flag
    size_t o_wih2 = alloc((size_t)G4_ * H_ * 2);      // 8 MB bf16 (for v-gemm)
    size_t o_xb   = alloc((size_t)B_ * T_ * F_ * 2);  // 32 MB (transposed [t][b][f])
    size_t o_b1s  = alloc(G4_ * 4);
    size_t o_b2s  = alloc(G4_ * 4);
    size_t o_ct   = alloc(B_ * T_ * 4);
    size_t o_ccb  = alloc(B_ * F_ * 2);
    size_t o_v    = alloc((size_t)B_ * G4_ * 4);      // 1 MB
    size_t o_h1   = alloc(2 * B_ * H_ * 2);
    size_t o_h2   = alloc(2 * B_ * H_ * 2);
    size_t o_outl = alloc(B_ * H_ * 4);
    size_t o_w1t  = alloc(64 * H_ * 2);
    size_t o_msm  = alloc(B_ * H_ * 4);
    size_t o_ssm  = alloc(B_ * H_ * 4);
    size_t o_tap  = alloc(B_ * T_ * 4);
    size_t o_enc  = alloc((size_t)B_ * T_ * H_ * 2);  // 32 MB bf16
    size_t o_saa  = o_xb;                             // alias: xb dead after recurrence
    size_t o_r1   = o_enc;                            // alias: enc dead after p2

    if (ws_size < off) return;  // fail loudly as absmax mismatch, never a fault

    unsigned* bar  = (unsigned*)(ws + o_bar);
    bf16_t* wih2b  = (bf16_t*)(ws + o_wih2);
    bf16_t* xb     = (bf16_t*)(ws + o_xb);
    float*  b1s    = (float*)(ws + o_b1s);
    float*  b2s    = (float*)(ws + o_b2s);
    float*  ctp    = (float*)(ws + o_ct);
    bf16_t* ccb    = (bf16_t*)(ws + o_ccb);
    float*  vbuf   = (float*)(ws + o_v);
    bf16_t* h1     = (bf16_t*)(ws + o_h1);
    bf16_t* h2     = (bf16_t*)(ws + o_h2);
    float*  outl   = (float*)(ws + o_outl);
    bf16_t* w1t    = (bf16_t*)(ws + o_w1t);
    float*  msm    = (float*)(ws + o_msm);
    float*  ssm    = (float*)(ws + o_ssm);
    float*  tap    = (float*)(ws + o_tap);
    bf16_t* encp   = (bf16_t*)(ws + o_enc);
    bf16_t* saa    = (bf16_t*)(ws + o_saa);
    float*  r1     = (float*)(ws + o_r1);

    hipMemsetAsync(ws + o_bar, 0, 4096, stream);

    int n = G4_ * H_;
    cast_kernel<<<(n + 255) / 256, 256, 0, stream>>>(W_ih2, wih2b, n);
    xt_kernel<<<B_ * T_ * F_ / 256, 256, 0, stream>>>(x, xb);
    bias_sum_kernel<<<16, 256, 0, stream>>>(b_ih1, b_hh1, b1s, G4_);
    bias_sum_kernel<<<16, 256, 0, stream>>>(b_ih2, b_hh2, b2s, G4_);
    cov1_kernel<<<B_ * T_ / 4, 256, 0, stream>>>(x, ctp);
    cov2_kernel<<<B_, 256, 0, stream>>>(x, ccb);
    w1t_kernel<<<256, 256, 0, stream>>>(w1, w1t);

    // v = cov_chan * Wih2^T (fp32 out)
    gemm_bt_kernel<<<dim3(G4_ / 64, 1), 256, 0, stream>>>(ccb, wih2b, nullptr, vbuf, B_, G4_, H_);

    lstm_recur_kernel<<<NBLK_, 256, 0, stream>>>(
        xb, ctp, vbuf, b1s, b2s, W_ih1, W_hh1, W_hh2, h1, h2, encp, outl, bar);

    p1_kernel<<<B_, 256, 0, stream>>>(encp, msm, ssm);
    p2_kernel<<<B_ * T_, 256, 0, stream>>>(encp, msm, ssm, outl, w_attn, saa, tap);
    // r1 = saa * w1T^T + b1 (fp32 out)
    gemm_bt_kernel<<<dim3(1, B_ * T_ / 128), 256, 0, stream>>>(saa, w1t, b1, r1, B_ * T_, 64, H_);
    p4_kernel<<<B_ * T_ / 4, 256, 0, stream>>>(r1, w2, b2, tap, b_attn, bar + 992, (float*)d_out);

    (void)in_sizes; (void)n_in; (void)out_size;
}